// Round 1
// baseline (496.840 us; speedup 1.0000x reference)
//
#include <hip/hip_runtime.h>
#include <hip/hip_bf16.h>

#define NEG_SLOPE 0.2f

// ---------------------------------------------------------------------------
// wv[k] = sum_j W_dst[k][j] * a_dst[j]   (collapse alpha_dst GEMM to matvec)
// ---------------------------------------------------------------------------
__global__ void make_wv(const float* __restrict__ W_dst,
                        const float* __restrict__ a_dst,
                        float* __restrict__ wv, int K) {
    int k = blockIdx.x * 64 + threadIdx.x;
    if (k < K) {
        float s = 0.f;
        #pragma unroll
        for (int j = 0; j < 64; ++j) s += W_dst[k * 64 + j] * a_dst[j];
        wv[k] = s;
    }
}

// ---------------------------------------------------------------------------
// CSR build: histogram -> block scans -> scatter
// ---------------------------------------------------------------------------
__global__ void hist_kernel(const int* __restrict__ dst, int* __restrict__ deg, int E) {
    int i = blockIdx.x * 256 + threadIdx.x;
    if (i < E) atomicAdd(&deg[dst[i]], 1);
}

__global__ void scan_blocks(const int* __restrict__ deg, int* __restrict__ bscan,
                            int* __restrict__ partials, int n) {
    __shared__ int tmp[256];
    int tid = threadIdx.x;
    int gid = blockIdx.x * 256 + tid;
    int v = (gid < n) ? deg[gid] : 0;
    tmp[tid] = v;
    __syncthreads();
    for (int off = 1; off < 256; off <<= 1) {
        int t = (tid >= off) ? tmp[tid - off] : 0;
        __syncthreads();
        tmp[tid] += t;
        __syncthreads();
    }
    if (gid < n) bscan[gid] = tmp[tid] - v;           // exclusive
    if (tid == 255) partials[blockIdx.x] = tmp[255];  // block total
}

// single block; nb <= 256 (N=50000 -> nb=196)
__global__ void scan_partials(int* __restrict__ partials, int nb,
                              int* __restrict__ row_ptr, int N) {
    __shared__ int tmp[256];
    int tid = threadIdx.x;
    int v = (tid < nb) ? partials[tid] : 0;
    tmp[tid] = v;
    __syncthreads();
    for (int off = 1; off < 256; off <<= 1) {
        int t = (tid >= off) ? tmp[tid - off] : 0;
        __syncthreads();
        tmp[tid] += t;
        __syncthreads();
    }
    if (tid < nb) partials[tid] = tmp[tid] - v;       // exclusive
    if (tid == 255) row_ptr[N] = tmp[255];            // total = E
}

__global__ void scan_finalize(const int* __restrict__ bscan,
                              const int* __restrict__ partials,
                              int* __restrict__ row_ptr, int* __restrict__ cursor, int n) {
    int i = blockIdx.x * 256 + threadIdx.x;
    if (i < n) {
        int v = bscan[i] + partials[i >> 8];
        row_ptr[i] = v;
        cursor[i]  = v;
    }
}

__global__ void scatter_kernel(const int* __restrict__ src, const int* __restrict__ dst,
                               int* __restrict__ cursor, int* __restrict__ csr_src, int E) {
    int i = blockIdx.x * 256 + threadIdx.x;
    if (i < E) {
        int p = atomicAdd(&cursor[dst[i]], 1);
        csr_src[p] = src[i];
    }
}

// ---------------------------------------------------------------------------
// Node transform: h = x@W_src ; alpha_src = h@a_src ; alpha_dst = x@wv
// wave per node, lane = output column (H=64)
// ---------------------------------------------------------------------------
template <int K>
__global__ __launch_bounds__(256) void node_transform(
    const float* __restrict__ x,        // [N][K]
    const float* __restrict__ W,        // [K][64]
    const float* __restrict__ a_src,    // [64]
    const float* __restrict__ wv,       // [K]
    float* __restrict__ h_out,          // [N][64]
    float* __restrict__ alpha_src,      // [N]
    float* __restrict__ alpha_dst,      // [N]
    int N) {
    __shared__ float sW[K * 64];
    __shared__ float sa[64];
    __shared__ float swv[K];
    __shared__ float sx[4][K];

    int tid = threadIdx.x;
    for (int i = tid; i < K * 64; i += 256) sW[i] = W[i];
    if (tid < 64) sa[tid] = a_src[tid];
    for (int i = tid; i < K; i += 256) swv[i] = wv[i];

    int wid = tid >> 6, lane = tid & 63;
    int node = blockIdx.x * 4 + wid;
    if (node < N) {
        const float* xr = x + (size_t)node * K;
        for (int k = lane; k < K; k += 64) sx[wid][k] = xr[k];
    }
    __syncthreads();
    if (node >= N) return;

    float acc = 0.f;
    #pragma unroll
    for (int k = 0; k < K; ++k) {
        acc += sx[wid][k] * sW[k * 64 + lane];
    }

    // alpha_dst = dot(x_row, wv) : lane-parallel + wave reduce
    float adp = 0.f;
    #pragma unroll
    for (int k = lane; k < K; k += 64) adp += sx[wid][k] * swv[k];
    #pragma unroll
    for (int off = 32; off; off >>= 1) adp += __shfl_xor(adp, off);

    // alpha_src = dot(h_row, a_src)
    float asp = acc * sa[lane];
    #pragma unroll
    for (int off = 32; off; off >>= 1) asp += __shfl_xor(asp, off);

    h_out[(size_t)node * 64 + lane] = acc;
    if (lane == 0) {
        alpha_src[node] = asp;
        alpha_dst[node] = adp;
    }
}

// ---------------------------------------------------------------------------
// Aggregation: wave per dst node, lane = feature. Online softmax in registers.
// out[i][:] = tanh( sum_e alpha_e * h_src[src_e][:] + bias )
// ---------------------------------------------------------------------------
__global__ __launch_bounds__(256) void aggregate(
    const int* __restrict__ row_ptr, const int* __restrict__ csr_src,
    const float* __restrict__ alpha_src, const float* __restrict__ alpha_dst,
    const float* __restrict__ h_src,    // [N][64]
    const float* __restrict__ bias,     // [64]
    float* __restrict__ out,            // [N][64]
    int N) {
    int wid = threadIdx.x >> 6, lane = threadIdx.x & 63;
    int node = blockIdx.x * 4 + wid;
    if (node >= N) return;

    int beg = row_ptr[node], end = row_ptr[node + 1];
    float adst = alpha_dst[node];
    float m = -1e30f, denom = 0.f, acc = 0.f;

    // 1-deep software prefetch
    int   s  = (beg < end) ? csr_src[beg] : 0;
    float as = 0.f, hs = 0.f;
    if (beg < end) {
        as = alpha_src[s];
        hs = h_src[(size_t)s * 64 + lane];
    }
    for (int e = beg; e < end; ++e) {
        float cur_as = as, cur_hs = hs;
        int e2 = e + 1;
        if (e2 < end) {
            int s2 = csr_src[e2];
            as = alpha_src[s2];
            hs = h_src[(size_t)s2 * 64 + lane];
        }
        float el = cur_as + adst;
        el = (el > 0.f) ? el : NEG_SLOPE * el;
        float mn = fmaxf(m, el);
        float sc = __expf(m - mn);    // underflows to 0 on first edge
        float p  = __expf(el - mn);
        denom = denom * sc + p;
        acc   = acc   * sc + p * cur_hs;
        m = mn;
    }
    float r = (denom > 0.f) ? (acc / denom) : 0.f;
    out[(size_t)node * 64 + lane] = tanhf(r + bias[lane]);
}

// ---------------------------------------------------------------------------
extern "C" void kernel_launch(void* const* d_in, const int* in_sizes, int n_in,
                              void* d_out, int out_size, void* d_ws, size_t ws_size,
                              hipStream_t stream) {
    const float* x      = (const float*)d_in[0];
    const int*   src    = (const int*)  d_in[1];
    const int*   dst    = (const int*)  d_in[2];
    const float* W1_src = (const float*)d_in[3];
    const float* W1_dst = (const float*)d_in[4];
    const float* a1_src = (const float*)d_in[5];
    const float* a1_dst = (const float*)d_in[6];
    const float* b1     = (const float*)d_in[7];
    const float* W2_src = (const float*)d_in[8];
    const float* W2_dst = (const float*)d_in[9];
    const float* a2_src = (const float*)d_in[10];
    const float* a2_dst = (const float*)d_in[11];
    const float* b2     = (const float*)d_in[12];
    float* out = (float*)d_out;

    const int N = in_sizes[0] / 128;
    const int E = in_sizes[1];

    // workspace layout (256-byte aligned slices)
    char* ws = (char*)d_ws;
    size_t off = 0;
    auto alloc = [&](size_t bytes) {
        void* p = ws + off;
        off += (bytes + 255) & ~(size_t)255;
        return p;
    };
    float* bufA      = (float*)alloc((size_t)N * 64 * 4);  // h_src (both layers)
    float* bufB      = (float*)alloc((size_t)N * 64 * 4);  // h1 (layer-1 output)
    float* alpha_src = (float*)alloc((size_t)N * 4);
    float* alpha_dst = (float*)alloc((size_t)N * 4);
    float* wv        = (float*)alloc(128 * 4);
    int*   deg       = (int*)  alloc((size_t)N * 4);
    int*   row_ptr   = (int*)  alloc((size_t)(N + 1) * 4);
    int*   cursor    = (int*)  alloc((size_t)N * 4);
    int*   bscan     = (int*)  alloc((size_t)N * 4);
    int*   partials  = (int*)  alloc(256 * 4);
    int*   csr_src   = (int*)  alloc((size_t)E * 4);
    (void)ws_size;

    const int nb    = (N + 255) / 256;       // 196 scan blocks
    const int eb    = (E + 255) / 256;
    const int nodeb = (N + 3) / 4;

    // ---- CSR build (graph is shared by both layers) ----
    hipMemsetAsync(deg, 0, (size_t)N * 4, stream);
    hist_kernel<<<eb, 256, 0, stream>>>(dst, deg, E);
    scan_blocks<<<nb, 256, 0, stream>>>(deg, bscan, partials, N);
    scan_partials<<<1, 256, 0, stream>>>(partials, nb, row_ptr, N);
    scan_finalize<<<nb, 256, 0, stream>>>(bscan, partials, row_ptr, cursor, N);
    scatter_kernel<<<eb, 256, 0, stream>>>(src, dst, cursor, csr_src, E);

    // ---- Layer 1 ----
    make_wv<<<2, 64, 0, stream>>>(W1_dst, a1_dst, wv, 128);
    node_transform<128><<<nodeb, 256, 0, stream>>>(x, W1_src, a1_src, wv,
                                                   bufA, alpha_src, alpha_dst, N);
    aggregate<<<nodeb, 256, 0, stream>>>(row_ptr, csr_src, alpha_src, alpha_dst,
                                         bufA, b1, bufB, N);

    // ---- Layer 2 ----
    make_wv<<<1, 64, 0, stream>>>(W2_dst, a2_dst, wv, 64);
    node_transform<64><<<nodeb, 256, 0, stream>>>(bufB, W2_src, a2_src, wv,
                                                  bufA, alpha_src, alpha_dst, N);
    aggregate<<<nodeb, 256, 0, stream>>>(row_ptr, csr_src, alpha_src, alpha_dst,
                                         bufA, b2, out, N);
}

// Round 2
// 328.189 us; speedup vs baseline: 1.5139x; 1.5139x over previous
//
#include <hip/hip_runtime.h>
#include <hip/hip_bf16.h>

#define NEG_SLOPE 0.2f

// ---------------------------------------------------------------------------
// wv[k] = sum_j W_dst[k][j] * a_dst[j]   (collapse alpha_dst GEMM to matvec)
// ---------------------------------------------------------------------------
__global__ void make_wv(const float* __restrict__ W_dst,
                        const float* __restrict__ a_dst,
                        float* __restrict__ wv, int K) {
    int k = blockIdx.x * 64 + threadIdx.x;
    if (k < K) {
        float s = 0.f;
        #pragma unroll
        for (int j = 0; j < 64; ++j) s += W_dst[k * 64 + j] * a_dst[j];
        wv[k] = s;
    }
}

// ---------------------------------------------------------------------------
// CSR build: histogram -> block scans -> scatter
// ---------------------------------------------------------------------------
__global__ void hist_kernel(const int* __restrict__ dst, int* __restrict__ deg, int E) {
    int i = blockIdx.x * 256 + threadIdx.x;
    if (i < E) atomicAdd(&deg[dst[i]], 1);
}

__global__ void scan_blocks(const int* __restrict__ deg, int* __restrict__ bscan,
                            int* __restrict__ partials, int n) {
    __shared__ int tmp[256];
    int tid = threadIdx.x;
    int gid = blockIdx.x * 256 + tid;
    int v = (gid < n) ? deg[gid] : 0;
    tmp[tid] = v;
    __syncthreads();
    for (int off = 1; off < 256; off <<= 1) {
        int t = (tid >= off) ? tmp[tid - off] : 0;
        __syncthreads();
        tmp[tid] += t;
        __syncthreads();
    }
    if (gid < n) bscan[gid] = tmp[tid] - v;           // exclusive
    if (tid == 255) partials[blockIdx.x] = tmp[255];  // block total
}

// single block; nb <= 256 (N=50000 -> nb=196)
__global__ void scan_partials(int* __restrict__ partials, int nb,
                              int* __restrict__ row_ptr, int N) {
    __shared__ int tmp[256];
    int tid = threadIdx.x;
    int v = (tid < nb) ? partials[tid] : 0;
    tmp[tid] = v;
    __syncthreads();
    for (int off = 1; off < 256; off <<= 1) {
        int t = (tid >= off) ? tmp[tid - off] : 0;
        __syncthreads();
        tmp[tid] += t;
        __syncthreads();
    }
    if (tid < nb) partials[tid] = tmp[tid] - v;       // exclusive
    if (tid == 255) row_ptr[N] = tmp[255];            // total = E
}

__global__ void scan_finalize(const int* __restrict__ bscan,
                              const int* __restrict__ partials,
                              int* __restrict__ row_ptr, int* __restrict__ cursor, int n) {
    int i = blockIdx.x * 256 + threadIdx.x;
    if (i < n) {
        int v = bscan[i] + partials[i >> 8];
        row_ptr[i] = v;
        cursor[i]  = v;
    }
}

__global__ void scatter_kernel(const int* __restrict__ src, const int* __restrict__ dst,
                               int* __restrict__ cursor, int* __restrict__ csr_src, int E) {
    int i = blockIdx.x * 256 + threadIdx.x;
    if (i < E) {
        int p = atomicAdd(&cursor[dst[i]], 1);
        csr_src[p] = src[i];
    }
}

// ---------------------------------------------------------------------------
// Node transform: h = x@W_src ; alpha_src = h@a_src ; alpha_dst = x@wv
// 4 waves/block, 4 nodes per wave (16 nodes/block). x rows read via
// wave-uniform scalar loads (readfirstlane'd node index); one sW ds_read
// per k feeds 4 FMAs.
// ---------------------------------------------------------------------------
template <int K>
__global__ __launch_bounds__(256) void node_transform(
    const float* __restrict__ x,        // [N][K]
    const float* __restrict__ W,        // [K][64]
    const float* __restrict__ a_src,    // [64]
    const float* __restrict__ wv,       // [K]
    float* __restrict__ h_out,          // [N][64]
    float* __restrict__ alpha_src,      // [N]
    float* __restrict__ alpha_dst,      // [N]
    int N) {
    __shared__ float sW[K * 64];
    __shared__ float sa[64];
    __shared__ float swv[K];

    int tid = threadIdx.x;
    for (int i = tid; i < K * 64; i += 256) sW[i] = W[i];
    if (tid < 64) sa[tid] = a_src[tid];
    for (int i = tid; i < K; i += 256) swv[i] = wv[i];
    __syncthreads();

    int wid = tid >> 6, lane = tid & 63;
    // wave-uniform base node index, forced into an SGPR
    int base = __builtin_amdgcn_readfirstlane(blockIdx.x * 16 + wid * 4);

    int n0 = base, n1 = base + 1, n2 = base + 2, n3 = base + 3;
    int c0 = (n0 < N) ? n0 : N - 1;
    int c1 = (n1 < N) ? n1 : N - 1;
    int c2 = (n2 < N) ? n2 : N - 1;
    int c3 = (n3 < N) ? n3 : N - 1;
    const float* xr0 = x + (size_t)c0 * K;
    const float* xr1 = x + (size_t)c1 * K;
    const float* xr2 = x + (size_t)c2 * K;
    const float* xr3 = x + (size_t)c3 * K;

    float acc0 = 0.f, acc1 = 0.f, acc2 = 0.f, acc3 = 0.f;
    #pragma unroll
    for (int kk = 0; kk < K; kk += 8) {
        float xs0[8], xs1[8], xs2[8], xs3[8];
        #pragma unroll
        for (int t = 0; t < 8; ++t) {
            xs0[t] = xr0[kk + t];
            xs1[t] = xr1[kk + t];
            xs2[t] = xr2[kk + t];
            xs3[t] = xr3[kk + t];
        }
        #pragma unroll
        for (int t = 0; t < 8; ++t) {
            float wvv = sW[(kk + t) * 64 + lane];
            acc0 = fmaf(xs0[t], wvv, acc0);
            acc1 = fmaf(xs1[t], wvv, acc1);
            acc2 = fmaf(xs2[t], wvv, acc2);
            acc3 = fmaf(xs3[t], wvv, acc3);
        }
    }

    // alpha_dst = dot(x_row, wv): lane-strided + wave reduce
    float ad0 = 0.f, ad1 = 0.f, ad2 = 0.f, ad3 = 0.f;
    #pragma unroll
    for (int k = lane; k < K; k += 64) {
        float wvk = swv[k];
        ad0 += xr0[k] * wvk;
        ad1 += xr1[k] * wvk;
        ad2 += xr2[k] * wvk;
        ad3 += xr3[k] * wvk;
    }
    #pragma unroll
    for (int off = 32; off; off >>= 1) {
        ad0 += __shfl_xor(ad0, off);
        ad1 += __shfl_xor(ad1, off);
        ad2 += __shfl_xor(ad2, off);
        ad3 += __shfl_xor(ad3, off);
    }

    // alpha_src = dot(h_row, a_src)
    float salane = sa[lane];
    float as0 = acc0 * salane, as1 = acc1 * salane;
    float as2 = acc2 * salane, as3 = acc3 * salane;
    #pragma unroll
    for (int off = 32; off; off >>= 1) {
        as0 += __shfl_xor(as0, off);
        as1 += __shfl_xor(as1, off);
        as2 += __shfl_xor(as2, off);
        as3 += __shfl_xor(as3, off);
    }

    if (n0 < N) h_out[(size_t)n0 * 64 + lane] = acc0;
    if (n1 < N) h_out[(size_t)n1 * 64 + lane] = acc1;
    if (n2 < N) h_out[(size_t)n2 * 64 + lane] = acc2;
    if (n3 < N) h_out[(size_t)n3 * 64 + lane] = acc3;
    if (lane == 0) {
        if (n0 < N) { alpha_src[n0] = as0; alpha_dst[n0] = ad0; }
        if (n1 < N) { alpha_src[n1] = as1; alpha_dst[n1] = ad1; }
        if (n2 < N) { alpha_src[n2] = as2; alpha_dst[n2] = ad2; }
        if (n3 < N) { alpha_src[n3] = as3; alpha_dst[n3] = ad3; }
    }
}

// ---------------------------------------------------------------------------
// Aggregation: wave per dst node. Chunk-of-64 lane-parallel softmax
// (lane = edge), then broadcast-FMA feature accumulation (lane = feature).
// out[i][:] = tanh( sum_e alpha_e * h_src[src_e][:] + bias )
// ---------------------------------------------------------------------------
__global__ __launch_bounds__(256) void aggregate(
    const int* __restrict__ row_ptr, const int* __restrict__ csr_src,
    const float* __restrict__ alpha_src, const float* __restrict__ alpha_dst,
    const float* __restrict__ h,        // [N][64]
    const float* __restrict__ bias,     // [64]
    float* __restrict__ out,            // [N][64]
    int N) {
    int wid = threadIdx.x >> 6, lane = threadIdx.x & 63;
    int node = blockIdx.x * 4 + wid;
    if (node >= N) return;

    int beg = row_ptr[node], end = row_ptr[node + 1];
    float adst = alpha_dst[node];
    float blane = bias[lane];

    float m = -1e30f, denom = 0.f;
    float acc0 = 0.f, acc1 = 0.f;

    for (int c = beg; c < end; c += 64) {
        int cnt = end - c;
        cnt = (cnt < 64) ? cnt : 64;

        // --- lane-parallel logits for this chunk (lane = edge) ---
        int s = 0;
        float el = -1e30f;
        if (lane < cnt) {
            s = csr_src[c + lane];
            float t = alpha_src[s] + adst;
            el = (t > 0.f) ? t : NEG_SLOPE * t;
        }
        // chunk max
        float cm = el;
        #pragma unroll
        for (int off = 32; off; off >>= 1) cm = fmaxf(cm, __shfl_xor(cm, off));
        float mn = fmaxf(m, cm);
        float scale = __expf(m - mn);   // 0 on first chunk
        float p = (lane < cnt) ? __expf(el - mn) : 0.f;
        // chunk sum
        float ps = p;
        #pragma unroll
        for (int off = 32; off; off >>= 1) ps += __shfl_xor(ps, off);
        denom = denom * scale + ps;
        acc0 *= scale;
        acc1 *= scale;
        m = mn;

        // --- feature accumulation (lane = feature), broadcast p/s per edge ---
        #pragma unroll
        for (int j = 0; j < 64; j += 2) {
            if (j >= cnt) break;
            float pj = __shfl(p, j);
            int   sj = __shfl(s, j);
            acc0 = fmaf(pj, h[(size_t)sj * 64 + lane], acc0);
            if (j + 1 < cnt) {
                float pk = __shfl(p, j + 1);
                int   sk = __shfl(s, j + 1);
                acc1 = fmaf(pk, h[(size_t)sk * 64 + lane], acc1);
            }
        }
    }
    float accs = acc0 + acc1;
    float r = (denom > 0.f) ? (accs / denom) : 0.f;
    out[(size_t)node * 64 + lane] = tanhf(r + blane);
}

// ---------------------------------------------------------------------------
extern "C" void kernel_launch(void* const* d_in, const int* in_sizes, int n_in,
                              void* d_out, int out_size, void* d_ws, size_t ws_size,
                              hipStream_t stream) {
    const float* x      = (const float*)d_in[0];
    const int*   src    = (const int*)  d_in[1];
    const int*   dst    = (const int*)  d_in[2];
    const float* W1_src = (const float*)d_in[3];
    const float* W1_dst = (const float*)d_in[4];
    const float* a1_src = (const float*)d_in[5];
    const float* a1_dst = (const float*)d_in[6];
    const float* b1     = (const float*)d_in[7];
    const float* W2_src = (const float*)d_in[8];
    const float* W2_dst = (const float*)d_in[9];
    const float* a2_src = (const float*)d_in[10];
    const float* a2_dst = (const float*)d_in[11];
    const float* b2     = (const float*)d_in[12];
    float* out = (float*)d_out;

    const int N = in_sizes[0] / 128;
    const int E = in_sizes[1];

    // workspace layout (256-byte aligned slices)
    char* ws = (char*)d_ws;
    size_t off = 0;
    auto alloc = [&](size_t bytes) {
        void* p = ws + off;
        off += (bytes + 255) & ~(size_t)255;
        return p;
    };
    float* bufA      = (float*)alloc((size_t)N * 64 * 4);  // h_src (both layers)
    float* bufB      = (float*)alloc((size_t)N * 64 * 4);  // h1 (layer-1 output)
    float* alpha_src = (float*)alloc((size_t)N * 4);
    float* alpha_dst = (float*)alloc((size_t)N * 4);
    float* wv        = (float*)alloc(128 * 4);
    int*   deg       = (int*)  alloc((size_t)N * 4);
    int*   row_ptr   = (int*)  alloc((size_t)(N + 1) * 4);
    int*   cursor    = (int*)  alloc((size_t)N * 4);
    int*   bscan     = (int*)  alloc((size_t)N * 4);
    int*   partials  = (int*)  alloc(256 * 4);
    int*   csr_src   = (int*)  alloc((size_t)E * 4);
    (void)ws_size;

    const int nb    = (N + 255) / 256;       // 196 scan blocks
    const int eb    = (E + 255) / 256;
    const int aggb  = (N + 3) / 4;           // aggregate: 4 nodes/block
    const int ntb   = (N + 15) / 16;         // node_transform: 16 nodes/block

    // ---- CSR build (graph is shared by both layers) ----
    hipMemsetAsync(deg, 0, (size_t)N * 4, stream);
    hist_kernel<<<eb, 256, 0, stream>>>(dst, deg, E);
    scan_blocks<<<nb, 256, 0, stream>>>(deg, bscan, partials, N);
    scan_partials<<<1, 256, 0, stream>>>(partials, nb, row_ptr, N);
    scan_finalize<<<nb, 256, 0, stream>>>(bscan, partials, row_ptr, cursor, N);
    scatter_kernel<<<eb, 256, 0, stream>>>(src, dst, cursor, csr_src, E);

    // ---- Layer 1 ----
    make_wv<<<2, 64, 0, stream>>>(W1_dst, a1_dst, wv, 128);
    node_transform<128><<<ntb, 256, 0, stream>>>(x, W1_src, a1_src, wv,
                                                 bufA, alpha_src, alpha_dst, N);
    aggregate<<<aggb, 256, 0, stream>>>(row_ptr, csr_src, alpha_src, alpha_dst,
                                        bufA, b1, bufB, N);

    // ---- Layer 2 ----
    make_wv<<<1, 64, 0, stream>>>(W2_dst, a2_dst, wv, 64);
    node_transform<64><<<ntb, 256, 0, stream>>>(bufB, W2_src, a2_src, wv,
                                                bufA, alpha_src, alpha_dst, N);
    aggregate<<<aggb, 256, 0, stream>>>(row_ptr, csr_src, alpha_src, alpha_dst,
                                        bufA, b2, out, N);
}

// Round 3
// 195.634 us; speedup vs baseline: 2.5396x; 1.6776x over previous
//
#include <hip/hip_runtime.h>
#include <hip/hip_bf16.h>

#define NEG_SLOPE 0.2f
#define EPB 4096   // edges per block in bucket_scatter (256 thr x 16)

// ---------------------------------------------------------------------------
// wv[k] = sum_j W_dst[k][j] * a_dst[j]   (collapse alpha_dst GEMM to matvec)
// ---------------------------------------------------------------------------
__global__ void make_wv(const float* __restrict__ W_dst,
                        const float* __restrict__ a_dst,
                        float* __restrict__ wv, int K) {
    int k = blockIdx.x * 64 + threadIdx.x;
    if (k < K) {
        float s = 0.f;
        #pragma unroll
        for (int j = 0; j < 64; ++j) s += W_dst[k * 64 + j] * a_dst[j];
        wv[k] = s;
    }
}

// ---------------------------------------------------------------------------
// CSR build via bucketed counting sort. bucket(node) = node >> 8.
// ---------------------------------------------------------------------------
// B1: per-bucket histogram, LDS-privatized
__global__ __launch_bounds__(256) void bucket_hist(const int* __restrict__ dst,
                                                   int* __restrict__ bucket_cnt, int E) {
    __shared__ int lh[256];
    int tid = threadIdx.x;
    lh[tid] = 0;
    __syncthreads();
    for (int e = blockIdx.x * 256 + tid; e < E; e += gridDim.x * 256)
        atomicAdd(&lh[dst[e] >> 8], 1);
    __syncthreads();
    if (lh[tid]) atomicAdd(&bucket_cnt[tid], lh[tid]);
}

// B2: exclusive scan of bucket counts (single block, NB <= 256)
__global__ __launch_bounds__(256) void bucket_scan(const int* __restrict__ bucket_cnt,
                                                   int* __restrict__ bucket_base,
                                                   int* __restrict__ bucket_cursor, int NB) {
    __shared__ int tmp[256];
    int tid = threadIdx.x;
    int v = (tid < NB) ? bucket_cnt[tid] : 0;
    tmp[tid] = v;
    __syncthreads();
    for (int off = 1; off < 256; off <<= 1) {
        int t = (tid >= off) ? tmp[tid - off] : 0;
        __syncthreads();
        tmp[tid] += t;
        __syncthreads();
    }
    int excl = tmp[tid] - v;
    bucket_base[tid] = excl;
    bucket_cursor[tid] = excl;
    if (tid == 255) bucket_base[256] = tmp[255];   // == E
}

// B3: scatter edges into bucket-dense runs, block-level reservation.
// ebuf entry = (dst&255)<<16 | src   (requires N <= 65536)
__global__ __launch_bounds__(256) void bucket_scatter(const int* __restrict__ src,
                                                      const int* __restrict__ dst,
                                                      int* __restrict__ bucket_cursor,
                                                      unsigned* __restrict__ ebuf, int E) {
    __shared__ int lhist[256];
    __shared__ int lbase[256];
    int tid = threadIdx.x;
    lhist[tid] = 0;
    __syncthreads();
    int base = blockIdx.x * EPB;
    int bkt[16], rank[16];
    unsigned pack[16];
    #pragma unroll
    for (int i = 0; i < 16; ++i) {
        int e = base + i * 256 + tid;
        bkt[i] = -1;
        if (e < E) {
            int d = dst[e], s = src[e];
            bkt[i]  = d >> 8;
            pack[i] = ((unsigned)(d & 255) << 16) | (unsigned)s;
            rank[i] = atomicAdd(&lhist[bkt[i]], 1);
        }
    }
    __syncthreads();
    int cnt = lhist[tid];
    if (cnt) lbase[tid] = atomicAdd(&bucket_cursor[tid], cnt);
    __syncthreads();
    #pragma unroll
    for (int i = 0; i < 16; ++i)
        if (bkt[i] >= 0) ebuf[lbase[bkt[i]] + rank[i]] = pack[i];
}

// B4: per bucket (block): row_ptr for its 256 nodes + csr_src scatter into
// the bucket's contiguous (L2-resident) run.
__global__ __launch_bounds__(256) void bucket_build(const unsigned* __restrict__ ebuf,
                                                    const int* __restrict__ bucket_base,
                                                    int* __restrict__ row_ptr,
                                                    int* __restrict__ csr_src,
                                                    int N, int E) {
    __shared__ int deg[256];
    __shared__ int cur[256];
    __shared__ int tmp[256];
    int b = blockIdx.x, tid = threadIdx.x;
    int ebase = bucket_base[b], eend = bucket_base[b + 1];
    deg[tid] = 0;
    __syncthreads();
    for (int e = ebase + tid; e < eend; e += 256)
        atomicAdd(&deg[ebuf[e] >> 16], 1);
    __syncthreads();
    int v = deg[tid];
    tmp[tid] = v;
    __syncthreads();
    for (int off = 1; off < 256; off <<= 1) {
        int t = (tid >= off) ? tmp[tid - off] : 0;
        __syncthreads();
        tmp[tid] += t;
        __syncthreads();
    }
    int excl = tmp[tid] - v;
    int node = b * 256 + tid;
    if (node < N) row_ptr[node] = ebase + excl;
    if (b == 0 && tid == 0) row_ptr[N] = E;
    cur[tid] = excl;
    __syncthreads();
    for (int e = ebase + tid; e < eend; e += 256) {
        unsigned pk = ebuf[e];
        int r = atomicAdd(&cur[pk >> 16], 1);
        csr_src[ebase + r] = (int)(pk & 0xFFFFu);
    }
}

// ---------------------------------------------------------------------------
// Node transform: h = x@W_src ; alpha_src = h@a_src ; alpha_dst = x@wv
// 4 waves/block, 4 nodes per wave (16 nodes/block).
// ---------------------------------------------------------------------------
template <int K>
__global__ __launch_bounds__(256) void node_transform(
    const float* __restrict__ x,        // [N][K]
    const float* __restrict__ W,        // [K][64]
    const float* __restrict__ a_src,    // [64]
    const float* __restrict__ wv,       // [K]
    float* __restrict__ h_out,          // [N][64]
    float* __restrict__ alpha_src,      // [N]
    float* __restrict__ alpha_dst,      // [N]
    int N) {
    __shared__ float sW[K * 64];
    __shared__ float sa[64];
    __shared__ float swv[K];

    int tid = threadIdx.x;
    for (int i = tid; i < K * 64; i += 256) sW[i] = W[i];
    if (tid < 64) sa[tid] = a_src[tid];
    for (int i = tid; i < K; i += 256) swv[i] = wv[i];
    __syncthreads();

    int wid = tid >> 6, lane = tid & 63;
    int base = __builtin_amdgcn_readfirstlane(blockIdx.x * 16 + wid * 4);

    int n0 = base, n1 = base + 1, n2 = base + 2, n3 = base + 3;
    int c0 = (n0 < N) ? n0 : N - 1;
    int c1 = (n1 < N) ? n1 : N - 1;
    int c2 = (n2 < N) ? n2 : N - 1;
    int c3 = (n3 < N) ? n3 : N - 1;
    const float* xr0 = x + (size_t)c0 * K;
    const float* xr1 = x + (size_t)c1 * K;
    const float* xr2 = x + (size_t)c2 * K;
    const float* xr3 = x + (size_t)c3 * K;

    float acc0 = 0.f, acc1 = 0.f, acc2 = 0.f, acc3 = 0.f;
    #pragma unroll
    for (int kk = 0; kk < K; kk += 8) {
        float xs0[8], xs1[8], xs2[8], xs3[8];
        #pragma unroll
        for (int t = 0; t < 8; ++t) {
            xs0[t] = xr0[kk + t];
            xs1[t] = xr1[kk + t];
            xs2[t] = xr2[kk + t];
            xs3[t] = xr3[kk + t];
        }
        #pragma unroll
        for (int t = 0; t < 8; ++t) {
            float wvv = sW[(kk + t) * 64 + lane];
            acc0 = fmaf(xs0[t], wvv, acc0);
            acc1 = fmaf(xs1[t], wvv, acc1);
            acc2 = fmaf(xs2[t], wvv, acc2);
            acc3 = fmaf(xs3[t], wvv, acc3);
        }
    }

    float ad0 = 0.f, ad1 = 0.f, ad2 = 0.f, ad3 = 0.f;
    #pragma unroll
    for (int k = lane; k < K; k += 64) {
        float wvk = swv[k];
        ad0 += xr0[k] * wvk;
        ad1 += xr1[k] * wvk;
        ad2 += xr2[k] * wvk;
        ad3 += xr3[k] * wvk;
    }
    #pragma unroll
    for (int off = 32; off; off >>= 1) {
        ad0 += __shfl_xor(ad0, off);
        ad1 += __shfl_xor(ad1, off);
        ad2 += __shfl_xor(ad2, off);
        ad3 += __shfl_xor(ad3, off);
    }

    float salane = sa[lane];
    float as0 = acc0 * salane, as1 = acc1 * salane;
    float as2 = acc2 * salane, as3 = acc3 * salane;
    #pragma unroll
    for (int off = 32; off; off >>= 1) {
        as0 += __shfl_xor(as0, off);
        as1 += __shfl_xor(as1, off);
        as2 += __shfl_xor(as2, off);
        as3 += __shfl_xor(as3, off);
    }

    if (n0 < N) h_out[(size_t)n0 * 64 + lane] = acc0;
    if (n1 < N) h_out[(size_t)n1 * 64 + lane] = acc1;
    if (n2 < N) h_out[(size_t)n2 * 64 + lane] = acc2;
    if (n3 < N) h_out[(size_t)n3 * 64 + lane] = acc3;
    if (lane == 0) {
        if (n0 < N) { alpha_src[n0] = as0; alpha_dst[n0] = ad0; }
        if (n1 < N) { alpha_src[n1] = as1; alpha_dst[n1] = ad1; }
        if (n2 < N) { alpha_src[n2] = as2; alpha_dst[n2] = ad2; }
        if (n3 < N) { alpha_src[n3] = as3; alpha_dst[n3] = ad3; }
    }
}

// ---------------------------------------------------------------------------
// Aggregation: wave per dst node. Chunk-of-64 lane-parallel softmax
// (lane = edge), then 8-wide batched gather-FMA (lane = feature).
// ---------------------------------------------------------------------------
__global__ __launch_bounds__(256) void aggregate(
    const int* __restrict__ row_ptr, const int* __restrict__ csr_src,
    const float* __restrict__ alpha_src, const float* __restrict__ alpha_dst,
    const float* __restrict__ h,        // [N][64]
    const float* __restrict__ bias,     // [64]
    float* __restrict__ out,            // [N][64]
    int N) {
    int wid = threadIdx.x >> 6, lane = threadIdx.x & 63;
    int node = blockIdx.x * 4 + wid;
    if (node >= N) return;

    int beg = row_ptr[node], end = row_ptr[node + 1];
    float adst = alpha_dst[node];
    float blane = bias[lane];

    float m = -1e30f, denom = 0.f;
    float a0 = 0.f, a1 = 0.f, a2 = 0.f, a3 = 0.f;
    float a4 = 0.f, a5 = 0.f, a6 = 0.f, a7 = 0.f;

    for (int c = beg; c < end; c += 64) {
        int cnt = end - c;
        cnt = (cnt < 64) ? cnt : 64;

        // --- lane-parallel logits (lane = edge) ---
        int s = 0;
        float el = -1e30f;
        if (lane < cnt) {
            s = csr_src[c + lane];
            float t = alpha_src[s] + adst;
            el = (t > 0.f) ? t : NEG_SLOPE * t;
        }
        float cm = el;
        #pragma unroll
        for (int off = 32; off; off >>= 1) cm = fmaxf(cm, __shfl_xor(cm, off));
        float mn = fmaxf(m, cm);
        float scale = __expf(m - mn);   // 0 on first chunk
        float p = (lane < cnt) ? __expf(el - mn) : 0.f;
        float ps = p;
        #pragma unroll
        for (int off = 32; off; off >>= 1) ps += __shfl_xor(ps, off);
        denom = denom * scale + ps;
        a0 *= scale; a1 *= scale; a2 *= scale; a3 *= scale;
        a4 *= scale; a5 *= scale; a6 *= scale; a7 *= scale;
        m = mn;

        // --- feature accumulation: 8 independent gathers in flight ---
        int j = 0;
        for (; j + 8 <= cnt; j += 8) {
            int s0 = __shfl(s, j),     s1 = __shfl(s, j + 1);
            int s2_ = __shfl(s, j + 2), s3_ = __shfl(s, j + 3);
            int s4_ = __shfl(s, j + 4), s5_ = __shfl(s, j + 5);
            int s6_ = __shfl(s, j + 6), s7_ = __shfl(s, j + 7);
            float p0 = __shfl(p, j),     p1 = __shfl(p, j + 1);
            float p2 = __shfl(p, j + 2), p3 = __shfl(p, j + 3);
            float p4 = __shfl(p, j + 4), p5 = __shfl(p, j + 5);
            float p6 = __shfl(p, j + 6), p7 = __shfl(p, j + 7);
            float v0 = h[(size_t)s0 * 64 + lane];
            float v1 = h[(size_t)s1 * 64 + lane];
            float v2 = h[(size_t)s2_ * 64 + lane];
            float v3 = h[(size_t)s3_ * 64 + lane];
            float v4 = h[(size_t)s4_ * 64 + lane];
            float v5 = h[(size_t)s5_ * 64 + lane];
            float v6 = h[(size_t)s6_ * 64 + lane];
            float v7 = h[(size_t)s7_ * 64 + lane];
            a0 = fmaf(p0, v0, a0); a1 = fmaf(p1, v1, a1);
            a2 = fmaf(p2, v2, a2); a3 = fmaf(p3, v3, a3);
            a4 = fmaf(p4, v4, a4); a5 = fmaf(p5, v5, a5);
            a6 = fmaf(p6, v6, a6); a7 = fmaf(p7, v7, a7);
        }
        for (; j < cnt; ++j) {
            int sj = __shfl(s, j);
            float pj = __shfl(p, j);
            a0 = fmaf(pj, h[(size_t)sj * 64 + lane], a0);
        }
    }
    float accs = ((a0 + a1) + (a2 + a3)) + ((a4 + a5) + (a6 + a7));
    float r = (denom > 0.f) ? (accs / denom) : 0.f;
    out[(size_t)node * 64 + lane] = tanhf(r + blane);
}

// ---------------------------------------------------------------------------
extern "C" void kernel_launch(void* const* d_in, const int* in_sizes, int n_in,
                              void* d_out, int out_size, void* d_ws, size_t ws_size,
                              hipStream_t stream) {
    const float* x      = (const float*)d_in[0];
    const int*   src    = (const int*)  d_in[1];
    const int*   dst    = (const int*)  d_in[2];
    const float* W1_src = (const float*)d_in[3];
    const float* W1_dst = (const float*)d_in[4];
    const float* a1_src = (const float*)d_in[5];
    const float* a1_dst = (const float*)d_in[6];
    const float* b1     = (const float*)d_in[7];
    const float* W2_src = (const float*)d_in[8];
    const float* W2_dst = (const float*)d_in[9];
    const float* a2_src = (const float*)d_in[10];
    const float* a2_dst = (const float*)d_in[11];
    const float* b2     = (const float*)d_in[12];
    float* out = (float*)d_out;

    const int N = in_sizes[0] / 128;
    const int E = in_sizes[1];
    const int NB = (N + 255) / 256;          // buckets (196)

    // workspace layout (256-byte aligned slices)
    char* ws = (char*)d_ws;
    size_t off = 0;
    auto alloc = [&](size_t bytes) {
        void* p = ws + off;
        off += (bytes + 255) & ~(size_t)255;
        return p;
    };
    float* bufA      = (float*)alloc((size_t)N * 64 * 4);  // h_src (both layers)
    float* bufB      = (float*)alloc((size_t)N * 64 * 4);  // h1; aliases ebuf
    float* alpha_src = (float*)alloc((size_t)N * 4);
    float* alpha_dst = (float*)alloc((size_t)N * 4);
    float* wv        = (float*)alloc(128 * 4);
    int*   row_ptr   = (int*)  alloc((size_t)(N + 1) * 4);
    int*   csr_src   = (int*)  alloc((size_t)E * 4);
    int*   bucket_cnt    = (int*)alloc(256 * 4);
    int*   bucket_base   = (int*)alloc(257 * 4);
    int*   bucket_cursor = (int*)alloc(256 * 4);
    unsigned* ebuf = (unsigned*)bufB;   // dead before bufB is first written
    (void)ws_size;

    const int eb3   = (E + EPB - 1) / EPB;   // bucket_scatter blocks
    const int aggb  = (N + 3) / 4;           // aggregate: 4 nodes/block
    const int ntb   = (N + 15) / 16;         // node_transform: 16 nodes/block

    // ---- CSR build (counting sort; graph shared by both layers) ----
    hipMemsetAsync(bucket_cnt, 0, 256 * 4, stream);
    bucket_hist<<<256, 256, 0, stream>>>(dst, bucket_cnt, E);
    bucket_scan<<<1, 256, 0, stream>>>(bucket_cnt, bucket_base, bucket_cursor, NB);
    bucket_scatter<<<eb3, 256, 0, stream>>>(src, dst, bucket_cursor, ebuf, E);
    bucket_build<<<NB, 256, 0, stream>>>(ebuf, bucket_base, row_ptr, csr_src, N, E);

    // ---- Layer 1 ----
    make_wv<<<2, 64, 0, stream>>>(W1_dst, a1_dst, wv, 128);
    node_transform<128><<<ntb, 256, 0, stream>>>(x, W1_src, a1_src, wv,
                                                 bufA, alpha_src, alpha_dst, N);
    aggregate<<<aggb, 256, 0, stream>>>(row_ptr, csr_src, alpha_src, alpha_dst,
                                        bufA, b1, bufB, N);

    // ---- Layer 2 ----
    make_wv<<<1, 64, 0, stream>>>(W2_dst, a2_dst, wv, 64);
    node_transform<64><<<ntb, 256, 0, stream>>>(bufB, W2_src, a2_src, wv,
                                                bufA, alpha_src, alpha_dst, N);
    aggregate<<<aggb, 256, 0, stream>>>(row_ptr, csr_src, alpha_src, alpha_dst,
                                        bufA, b2, out, N);
}

// Round 4
// 181.654 us; speedup vs baseline: 2.7351x; 1.0770x over previous
//
#include <hip/hip_runtime.h>
#include <hip/hip_bf16.h>

#define NEG_SLOPE 0.2f
#define EPB 4096   // edges per block in bucket_scatter (256 thr x 16)

__device__ inline float blo(unsigned u) { return __uint_as_float(u << 16); }
__device__ inline float bhi(unsigned u) { return __uint_as_float(u & 0xffff0000u); }
__device__ inline unsigned pack2bf(float e, float o) {
    __hip_bfloat16 be = __float2bfloat16(e);
    __hip_bfloat16 bo = __float2bfloat16(o);
    unsigned le = *(unsigned short*)&be;
    unsigned lo_ = *(unsigned short*)&bo;
    return (lo_ << 16) | le;
}

// ---------------------------------------------------------------------------
// CSR build via bucketed counting sort. bucket(node) = node >> 8.
// ---------------------------------------------------------------------------
__global__ __launch_bounds__(256) void bucket_hist(const int* __restrict__ dst,
                                                   int* __restrict__ bucket_cnt, int E) {
    __shared__ int lh[256];
    int tid = threadIdx.x;
    lh[tid] = 0;
    __syncthreads();
    for (int e = blockIdx.x * 256 + tid; e < E; e += gridDim.x * 256)
        atomicAdd(&lh[dst[e] >> 8], 1);
    __syncthreads();
    if (lh[tid]) atomicAdd(&bucket_cnt[tid], lh[tid]);
}

__global__ __launch_bounds__(256) void bucket_scan(const int* __restrict__ bucket_cnt,
                                                   int* __restrict__ bucket_base,
                                                   int* __restrict__ bucket_cursor, int NB) {
    __shared__ int tmp[256];
    int tid = threadIdx.x;
    int v = (tid < NB) ? bucket_cnt[tid] : 0;
    tmp[tid] = v;
    __syncthreads();
    for (int off = 1; off < 256; off <<= 1) {
        int t = (tid >= off) ? tmp[tid - off] : 0;
        __syncthreads();
        tmp[tid] += t;
        __syncthreads();
    }
    int excl = tmp[tid] - v;
    bucket_base[tid] = excl;
    bucket_cursor[tid] = excl;
    if (tid == 255) bucket_base[256] = tmp[255];   // == E
}

// ebuf entry = (dst&255)<<16 | src   (requires N <= 65536)
__global__ __launch_bounds__(256) void bucket_scatter(const int* __restrict__ src,
                                                      const int* __restrict__ dst,
                                                      int* __restrict__ bucket_cursor,
                                                      unsigned* __restrict__ ebuf, int E) {
    __shared__ int lhist[256];
    __shared__ int lbase[256];
    int tid = threadIdx.x;
    lhist[tid] = 0;
    __syncthreads();
    int base = blockIdx.x * EPB;
    int bkt[16], rank[16];
    unsigned pack[16];
    #pragma unroll
    for (int i = 0; i < 16; ++i) {
        int e = base + i * 256 + tid;
        bkt[i] = -1;
        if (e < E) {
            int d = dst[e], s = src[e];
            bkt[i]  = d >> 8;
            pack[i] = ((unsigned)(d & 255) << 16) | (unsigned)s;
            rank[i] = atomicAdd(&lhist[bkt[i]], 1);
        }
    }
    __syncthreads();
    int cnt = lhist[tid];
    if (cnt) lbase[tid] = atomicAdd(&bucket_cursor[tid], cnt);
    __syncthreads();
    #pragma unroll
    for (int i = 0; i < 16; ++i)
        if (bkt[i] >= 0) ebuf[lbase[bkt[i]] + rank[i]] = pack[i];
}

__global__ __launch_bounds__(256) void bucket_build(const unsigned* __restrict__ ebuf,
                                                    const int* __restrict__ bucket_base,
                                                    int* __restrict__ row_ptr,
                                                    int* __restrict__ csr_src,
                                                    int N, int E) {
    __shared__ int deg[256];
    __shared__ int cur[256];
    __shared__ int tmp[256];
    int b = blockIdx.x, tid = threadIdx.x;
    int ebase = bucket_base[b], eend = bucket_base[b + 1];
    deg[tid] = 0;
    __syncthreads();
    for (int e = ebase + tid; e < eend; e += 256)
        atomicAdd(&deg[ebuf[e] >> 16], 1);
    __syncthreads();
    int v = deg[tid];
    tmp[tid] = v;
    __syncthreads();
    for (int off = 1; off < 256; off <<= 1) {
        int t = (tid >= off) ? tmp[tid - off] : 0;
        __syncthreads();
        tmp[tid] += t;
        __syncthreads();
    }
    int excl = tmp[tid] - v;
    int node = b * 256 + tid;
    if (node < N) row_ptr[node] = ebase + excl;
    if (b == 0 && tid == 0) row_ptr[N] = E;
    cur[tid] = excl;
    __syncthreads();
    for (int e = ebase + tid; e < eend; e += 256) {
        unsigned pk = ebuf[e];
        int r = atomicAdd(&cur[pk >> 16], 1);
        csr_src[ebase + r] = (int)(pk & 0xFFFFu);
    }
}

// ---------------------------------------------------------------------------
// Node transform: h = x@W_src (packed bf16 out); alpha_src = h@a_src;
// alpha_dst = x@(W_dst@a_dst). 4 waves/block, 4 nodes per wave.
// ---------------------------------------------------------------------------
template <int K>
__global__ __launch_bounds__(256) void node_transform(
    const float* __restrict__ x,        // [N][K]
    const float* __restrict__ W,        // [K][64]
    const float* __restrict__ a_src,    // [64]
    const float* __restrict__ W_dst,    // [K][64]
    const float* __restrict__ a_dst,    // [64]
    unsigned* __restrict__ hb_out,      // [N][32] packed bf16x2
    float* __restrict__ alpha_src,      // [N]
    float* __restrict__ alpha_dst,      // [N]
    int N) {
    __shared__ float sW[K * 64];
    __shared__ float sa[64];
    __shared__ float swv[K];

    int tid = threadIdx.x;
    for (int i = tid; i < K * 64; i += 256) sW[i] = W[i];
    if (tid < 64) sa[tid] = a_src[tid];
    // swv[k] = dot(W_dst[k,:], a_dst)
    for (int k = tid; k < K; k += 256) {
        float s = 0.f;
        #pragma unroll
        for (int j = 0; j < 64; ++j) s += W_dst[k * 64 + j] * a_dst[j];
        swv[k] = s;
    }
    __syncthreads();

    int wid = tid >> 6, lane = tid & 63;
    int base = __builtin_amdgcn_readfirstlane(blockIdx.x * 16 + wid * 4);

    int n0 = base, n1 = base + 1, n2 = base + 2, n3 = base + 3;
    int c0 = (n0 < N) ? n0 : N - 1;
    int c1 = (n1 < N) ? n1 : N - 1;
    int c2 = (n2 < N) ? n2 : N - 1;
    int c3 = (n3 < N) ? n3 : N - 1;
    const float* xr0 = x + (size_t)c0 * K;
    const float* xr1 = x + (size_t)c1 * K;
    const float* xr2 = x + (size_t)c2 * K;
    const float* xr3 = x + (size_t)c3 * K;

    float acc0 = 0.f, acc1 = 0.f, acc2 = 0.f, acc3 = 0.f;
    #pragma unroll
    for (int kk = 0; kk < K; kk += 8) {
        float xs0[8], xs1[8], xs2[8], xs3[8];
        #pragma unroll
        for (int t = 0; t < 8; ++t) {
            xs0[t] = xr0[kk + t];
            xs1[t] = xr1[kk + t];
            xs2[t] = xr2[kk + t];
            xs3[t] = xr3[kk + t];
        }
        #pragma unroll
        for (int t = 0; t < 8; ++t) {
            float wvv = sW[(kk + t) * 64 + lane];
            acc0 = fmaf(xs0[t], wvv, acc0);
            acc1 = fmaf(xs1[t], wvv, acc1);
            acc2 = fmaf(xs2[t], wvv, acc2);
            acc3 = fmaf(xs3[t], wvv, acc3);
        }
    }

    float ad0 = 0.f, ad1 = 0.f, ad2 = 0.f, ad3 = 0.f;
    #pragma unroll
    for (int k = lane; k < K; k += 64) {
        float wvk = swv[k];
        ad0 += xr0[k] * wvk;
        ad1 += xr1[k] * wvk;
        ad2 += xr2[k] * wvk;
        ad3 += xr3[k] * wvk;
    }
    #pragma unroll
    for (int off = 32; off; off >>= 1) {
        ad0 += __shfl_xor(ad0, off);
        ad1 += __shfl_xor(ad1, off);
        ad2 += __shfl_xor(ad2, off);
        ad3 += __shfl_xor(ad3, off);
    }

    float salane = sa[lane];
    float as0 = acc0 * salane, as1 = acc1 * salane;
    float as2 = acc2 * salane, as3 = acc3 * salane;
    #pragma unroll
    for (int off = 32; off; off >>= 1) {
        as0 += __shfl_xor(as0, off);
        as1 += __shfl_xor(as1, off);
        as2 += __shfl_xor(as2, off);
        as3 += __shfl_xor(as3, off);
    }

    // pack bf16 pairs: lane<32 writes u32 holding features (2*lane, 2*lane+1)
    int sub = lane & 31;
    float e0 = __shfl(acc0, 2 * sub), o0 = __shfl(acc0, 2 * sub + 1);
    float e1 = __shfl(acc1, 2 * sub), o1 = __shfl(acc1, 2 * sub + 1);
    float e2 = __shfl(acc2, 2 * sub), o2 = __shfl(acc2, 2 * sub + 1);
    float e3 = __shfl(acc3, 2 * sub), o3 = __shfl(acc3, 2 * sub + 1);
    if (lane < 32) {
        if (n0 < N) hb_out[(size_t)n0 * 32 + sub] = pack2bf(e0, o0);
        if (n1 < N) hb_out[(size_t)n1 * 32 + sub] = pack2bf(e1, o1);
        if (n2 < N) hb_out[(size_t)n2 * 32 + sub] = pack2bf(e2, o2);
        if (n3 < N) hb_out[(size_t)n3 * 32 + sub] = pack2bf(e3, o3);
    }
    if (lane == 0) {
        if (n0 < N) { alpha_src[n0] = as0; alpha_dst[n0] = ad0; }
        if (n1 < N) { alpha_src[n1] = as1; alpha_dst[n1] = ad1; }
        if (n2 < N) { alpha_src[n2] = as2; alpha_dst[n2] = ad2; }
        if (n3 < N) { alpha_src[n3] = as3; alpha_dst[n3] = ad3; }
    }
}

// ---------------------------------------------------------------------------
// Aggregation: wave per dst node. Chunk-of-64 lane-parallel softmax
// (lane = edge); gather phase: half-wave per edge, lane = u32 (2 bf16 feats).
// ---------------------------------------------------------------------------
__global__ __launch_bounds__(256) void aggregate(
    const int* __restrict__ row_ptr, const int* __restrict__ csr_src,
    const float* __restrict__ alpha_src, const float* __restrict__ alpha_dst,
    const unsigned* __restrict__ hb,    // [N][32] packed bf16x2
    const float* __restrict__ bias,     // [64]
    float* __restrict__ out,            // [N][64]
    int N) {
    int wid = threadIdx.x >> 6, lane = threadIdx.x & 63;
    int node = blockIdx.x * 4 + wid;
    if (node >= N) return;

    int beg = row_ptr[node], end = row_ptr[node + 1];
    float adst = alpha_dst[node];
    int half = lane >> 5, sub = lane & 31;

    float m = -1e30f, denom = 0.f;
    float aA0 = 0.f, aB0 = 0.f, aA1 = 0.f, aB1 = 0.f;
    float aA2 = 0.f, aB2 = 0.f, aA3 = 0.f, aB3 = 0.f;

    for (int c = beg; c < end; c += 64) {
        int cnt = end - c;
        cnt = (cnt < 64) ? cnt : 64;

        // --- lane-parallel logits (lane = edge) ---
        int s = 0;
        float el = -1e30f;
        if (lane < cnt) {
            s = csr_src[c + lane];
            float t = alpha_src[s] + adst;
            el = (t > 0.f) ? t : NEG_SLOPE * t;
        }
        float cm = el;
        #pragma unroll
        for (int off = 32; off; off >>= 1) cm = fmaxf(cm, __shfl_xor(cm, off));
        float mn = fmaxf(m, cm);
        float scale = __expf(m - mn);   // 0 on first chunk
        float p = (lane < cnt) ? __expf(el - mn) : 0.f;
        float ps = p;
        #pragma unroll
        for (int off = 32; off; off >>= 1) ps += __shfl_xor(ps, off);
        denom = denom * scale + ps;
        aA0 *= scale; aB0 *= scale; aA1 *= scale; aB1 *= scale;
        aA2 *= scale; aB2 *= scale; aA3 *= scale; aB3 *= scale;
        m = mn;

        // --- gather: 2 edges per step (half-wave each), 4 steps in flight ---
        int j = 0;
        for (; j + 8 <= cnt; j += 8) {
            int e0 = j + half, e1 = j + 2 + half, e2 = j + 4 + half, e3 = j + 6 + half;
            int s0 = __shfl(s, e0), s1 = __shfl(s, e1);
            int s2 = __shfl(s, e2), s3 = __shfl(s, e3);
            float p0 = __shfl(p, e0), p1 = __shfl(p, e1);
            float p2 = __shfl(p, e2), p3 = __shfl(p, e3);
            unsigned u0 = hb[(size_t)s0 * 32 + sub];
            unsigned u1 = hb[(size_t)s1 * 32 + sub];
            unsigned u2 = hb[(size_t)s2 * 32 + sub];
            unsigned u3 = hb[(size_t)s3 * 32 + sub];
            aA0 = fmaf(p0, blo(u0), aA0); aB0 = fmaf(p0, bhi(u0), aB0);
            aA1 = fmaf(p1, blo(u1), aA1); aB1 = fmaf(p1, bhi(u1), aB1);
            aA2 = fmaf(p2, blo(u2), aA2); aB2 = fmaf(p2, bhi(u2), aB2);
            aA3 = fmaf(p3, blo(u3), aA3); aB3 = fmaf(p3, bhi(u3), aB3);
        }
        for (; j < cnt; j += 2) {
            int e = j + half;
            int ec = (e < cnt) ? e : j;
            float pe = __shfl(p, ec);
            if (e >= cnt) pe = 0.f;
            int se = __shfl(s, ec);
            unsigned u = hb[(size_t)se * 32 + sub];
            aA0 = fmaf(pe, blo(u), aA0);
            aB0 = fmaf(pe, bhi(u), aB0);
        }
    }
    float accA = (aA0 + aA1) + (aA2 + aA3);
    float accB = (aB0 + aB1) + (aB2 + aB3);
    accA += __shfl_xor(accA, 32);
    accB += __shfl_xor(accB, 32);
    // lane wants feature `lane`, held by lane>>1 (even->A, odd->B)
    int srcl = lane >> 1;
    float vA = __shfl(accA, srcl);
    float vB = __shfl(accB, srcl);
    float val = (lane & 1) ? vB : vA;
    float r = (denom > 0.f) ? (val / denom) : 0.f;
    out[(size_t)node * 64 + lane] = tanhf(r + bias[lane]);
}

// ---------------------------------------------------------------------------
extern "C" void kernel_launch(void* const* d_in, const int* in_sizes, int n_in,
                              void* d_out, int out_size, void* d_ws, size_t ws_size,
                              hipStream_t stream) {
    const float* x      = (const float*)d_in[0];
    const int*   src    = (const int*)  d_in[1];
    const int*   dst    = (const int*)  d_in[2];
    const float* W1_src = (const float*)d_in[3];
    const float* W1_dst = (const float*)d_in[4];
    const float* a1_src = (const float*)d_in[5];
    const float* a1_dst = (const float*)d_in[6];
    const float* b1     = (const float*)d_in[7];
    const float* W2_src = (const float*)d_in[8];
    const float* W2_dst = (const float*)d_in[9];
    const float* a2_src = (const float*)d_in[10];
    const float* a2_dst = (const float*)d_in[11];
    const float* b2     = (const float*)d_in[12];
    float* out = (float*)d_out;

    const int N = in_sizes[0] / 128;
    const int E = in_sizes[1];
    const int NB = (N + 255) / 256;          // buckets (196)

    // workspace layout (256-byte aligned slices)
    char* ws = (char*)d_ws;
    size_t off = 0;
    auto alloc = [&](size_t bytes) {
        void* p = ws + off;
        off += (bytes + 255) & ~(size_t)255;
        return p;
    };
    unsigned* hbuf   = (unsigned*)alloc((size_t)N * 32 * 4);  // packed bf16 h
    float* bufB      = (float*)alloc((size_t)N * 64 * 4);     // h1; aliases ebuf
    float* alpha_src = (float*)alloc((size_t)N * 4);
    float* alpha_dst = (float*)alloc((size_t)N * 4);
    int*   row_ptr   = (int*)  alloc((size_t)(N + 1) * 4);
    int*   csr_src   = (int*)  alloc((size_t)E * 4);
    int*   bucket_cnt    = (int*)alloc(256 * 4);
    int*   bucket_base   = (int*)alloc(257 * 4);
    int*   bucket_cursor = (int*)alloc(256 * 4);
    unsigned* ebuf = (unsigned*)bufB;   // dead before bufB is first written
    (void)ws_size;

    const int eb3   = (E + EPB - 1) / EPB;   // bucket_scatter blocks
    const int aggb  = (N + 3) / 4;           // aggregate: 4 nodes/block
    const int ntb   = (N + 15) / 16;         // node_transform: 16 nodes/block

    // ---- CSR build (counting sort; graph shared by both layers) ----
    hipMemsetAsync(bucket_cnt, 0, 256 * 4, stream);
    bucket_hist<<<256, 256, 0, stream>>>(dst, bucket_cnt, E);
    bucket_scan<<<1, 256, 0, stream>>>(bucket_cnt, bucket_base, bucket_cursor, NB);
    bucket_scatter<<<eb3, 256, 0, stream>>>(src, dst, bucket_cursor, ebuf, E);
    bucket_build<<<NB, 256, 0, stream>>>(ebuf, bucket_base, row_ptr, csr_src, N, E);

    // ---- Layer 1 ----
    node_transform<128><<<ntb, 256, 0, stream>>>(x, W1_src, a1_src, W1_dst, a1_dst,
                                                 hbuf, alpha_src, alpha_dst, N);
    aggregate<<<aggb, 256, 0, stream>>>(row_ptr, csr_src, alpha_src, alpha_dst,
                                        hbuf, b1, bufB, N);

    // ---- Layer 2 ----
    node_transform<64><<<ntb, 256, 0, stream>>>(bufB, W2_src, a2_src, W2_dst, a2_dst,
                                                hbuf, alpha_src, alpha_dst, N);
    aggregate<<<aggb, 256, 0, stream>>>(row_ptr, csr_src, alpha_src, alpha_dst,
                                        hbuf, b2, out, N);
}

// Round 5
// 158.214 us; speedup vs baseline: 3.1403x; 1.1482x over previous
//
#include <hip/hip_runtime.h>
#include <hip/hip_bf16.h>

#define NEG_SLOPE 0.2f
#define EPB 4096   // edges per block in bucket_scatter (256 thr x 16)

typedef __attribute__((ext_vector_type(8))) short short8v;   // 8 bf16 bit-patterns
typedef __attribute__((ext_vector_type(4))) float f32x4;

__device__ inline float blo(unsigned u) { return __uint_as_float(u << 16); }
__device__ inline float bhi(unsigned u) { return __uint_as_float(u & 0xffff0000u); }
__device__ inline unsigned short bf16bits(float f) {
    __hip_bfloat16 b = __float2bfloat16(f);
    return *(unsigned short*)&b;
}
__device__ inline unsigned pack2bf(float e, float o) {
    return ((unsigned)bf16bits(o) << 16) | (unsigned)bf16bits(e);
}

// ---------------------------------------------------------------------------
// CSR build via bucketed counting sort. bucket(node) = node >> 8.
// ---------------------------------------------------------------------------
__global__ void init_counts(int* __restrict__ bucket_cnt) {
    bucket_cnt[threadIdx.x] = 0;
}

__global__ __launch_bounds__(256) void bucket_hist(const int* __restrict__ dst,
                                                   int* __restrict__ bucket_cnt, int E) {
    __shared__ int lh[256];
    int tid = threadIdx.x;
    lh[tid] = 0;
    __syncthreads();
    for (int e = blockIdx.x * 256 + tid; e < E; e += gridDim.x * 256)
        atomicAdd(&lh[dst[e] >> 8], 1);
    __syncthreads();
    if (lh[tid]) atomicAdd(&bucket_cnt[tid], lh[tid]);
}

__global__ __launch_bounds__(256) void bucket_scan(const int* __restrict__ bucket_cnt,
                                                   int* __restrict__ bucket_base,
                                                   int* __restrict__ bucket_cursor, int NB) {
    __shared__ int tmp[256];
    int tid = threadIdx.x;
    int v = (tid < NB) ? bucket_cnt[tid] : 0;
    tmp[tid] = v;
    __syncthreads();
    for (int off = 1; off < 256; off <<= 1) {
        int t = (tid >= off) ? tmp[tid - off] : 0;
        __syncthreads();
        tmp[tid] += t;
        __syncthreads();
    }
    int excl = tmp[tid] - v;
    bucket_base[tid] = excl;
    bucket_cursor[tid] = excl;
    if (tid == 255) bucket_base[256] = tmp[255];   // == E
}

// ebuf entry = (dst&255)<<16 | src   (requires N <= 65536)
__global__ __launch_bounds__(256) void bucket_scatter(const int* __restrict__ src,
                                                      const int* __restrict__ dst,
                                                      int* __restrict__ bucket_cursor,
                                                      unsigned* __restrict__ ebuf, int E) {
    __shared__ int lhist[256];
    __shared__ int lbase[256];
    int tid = threadIdx.x;
    lhist[tid] = 0;
    __syncthreads();
    int base = blockIdx.x * EPB;
    int bkt[16], rank[16];
    unsigned pack[16];
    #pragma unroll
    for (int i = 0; i < 16; ++i) {
        int e = base + i * 256 + tid;
        bkt[i] = -1;
        if (e < E) {
            int d = dst[e], s = src[e];
            bkt[i]  = d >> 8;
            pack[i] = ((unsigned)(d & 255) << 16) | (unsigned)s;
            rank[i] = atomicAdd(&lhist[bkt[i]], 1);
        }
    }
    __syncthreads();
    int cnt = lhist[tid];
    if (cnt) lbase[tid] = atomicAdd(&bucket_cursor[tid], cnt);
    __syncthreads();
    #pragma unroll
    for (int i = 0; i < 16; ++i)
        if (bkt[i] >= 0) ebuf[lbase[bkt[i]] + rank[i]] = pack[i];
}

__global__ __launch_bounds__(256) void bucket_build(const unsigned* __restrict__ ebuf,
                                                    const int* __restrict__ bucket_base,
                                                    int* __restrict__ row_ptr,
                                                    int* __restrict__ csr_src,
                                                    int N, int E) {
    __shared__ int deg[256];
    __shared__ int cur[256];
    __shared__ int tmp[256];
    int b = blockIdx.x, tid = threadIdx.x;
    int ebase = bucket_base[b], eend = bucket_base[b + 1];
    deg[tid] = 0;
    __syncthreads();
    for (int e = ebase + tid; e < eend; e += 256)
        atomicAdd(&deg[ebuf[e] >> 16], 1);
    __syncthreads();
    int v = deg[tid];
    tmp[tid] = v;
    __syncthreads();
    for (int off = 1; off < 256; off <<= 1) {
        int t = (tid >= off) ? tmp[tid - off] : 0;
        __syncthreads();
        tmp[tid] += t;
        __syncthreads();
    }
    int excl = tmp[tid] - v;
    int node = b * 256 + tid;
    if (node < N) row_ptr[node] = ebase + excl;
    if (b == 0 && tid == 0) row_ptr[N] = E;
    cur[tid] = excl;
    __syncthreads();
    for (int e = ebase + tid; e < eend; e += 256) {
        unsigned pk = ebuf[e];
        int r = atomicAdd(&cur[pk >> 16], 1);
        csr_src[ebase + r] = (int)(pk & 0xFFFFu);
    }
}

// ---------------------------------------------------------------------------
// Node transform via MFMA (bf16 in, fp32 accum):
//   h = x@W_src (packed bf16 out), alpha_src = x@(W_src@a_src) [col 64],
//   alpha_dst = x@(W_dst@a_dst) [col 65].
// 4 waves/block, wave = 16 rows x 80 cols (5 MFMA col-tiles).
// B^T staged bf16 in LDS, K-major, PAD=K+8 to de-conflict ds_read_b128.
// ---------------------------------------------------------------------------
template <int K>
__global__ __launch_bounds__(256) void node_transform_mfma(
    const float* __restrict__ x,        // [N][K]
    const float* __restrict__ W_src,    // [K][64]
    const float* __restrict__ a_src,    // [64]
    const float* __restrict__ W_dst,    // [K][64]
    const float* __restrict__ a_dst,    // [64]
    unsigned* __restrict__ hb_out,      // [N][32] packed bf16x2
    float* __restrict__ alpha_src,      // [N]
    float* __restrict__ alpha_dst,      // [N]
    int N) {
    constexpr int PAD = K + 8;
    __shared__ unsigned short sBt[80 * PAD];

    int tid = threadIdx.x;
    // cols 0..63 = W_src^T (coalesced global read, ushort LDS write)
    for (int i = tid; i < 64 * K; i += 256) {
        int k = i >> 6, j = i & 63;
        sBt[j * PAD + k] = bf16bits(W_src[i]);
    }
    // col 64 = W_src@a_src, col 65 = W_dst@a_dst
    for (int i = tid; i < 2 * K; i += 256) {
        int which = (i >= K) ? 1 : 0;
        int k = i - which * K;
        const float* Wr = (which ? W_dst : W_src) + k * 64;
        const float* av = which ? a_dst : a_src;
        float s = 0.f;
        #pragma unroll
        for (int j = 0; j < 64; ++j) s += Wr[j] * av[j];
        sBt[(64 + which) * PAD + k] = bf16bits(s);
    }
    // cols 66..79 = 0
    for (int i = tid; i < 14 * K; i += 256) {
        int j = 66 + i / K, k = i % K;
        sBt[j * PAD + k] = 0;
    }
    __syncthreads();

    int wid = tid >> 6, l = tid & 63;
    int rowbase = blockIdx.x * 64 + wid * 16;
    int r_load = rowbase + (l & 15);
    if (r_load >= N) r_load = N - 1;          // clamp (stores are guarded)
    int kgrp = (l >> 4) * 8;

    f32x4 acc[5];
    #pragma unroll
    for (int t = 0; t < 5; ++t) acc[t] = (f32x4){0.f, 0.f, 0.f, 0.f};

    const float* xr = x + (size_t)r_load * K + kgrp;
    int jcol = l & 15;
    #pragma unroll
    for (int kt = 0; kt < K / 32; ++kt) {
        float4 xa = *(const float4*)(xr + kt * 32);
        float4 xb = *(const float4*)(xr + kt * 32 + 4);
        short8v a;
        a[0] = (short)bf16bits(xa.x); a[1] = (short)bf16bits(xa.y);
        a[2] = (short)bf16bits(xa.z); a[3] = (short)bf16bits(xa.w);
        a[4] = (short)bf16bits(xb.x); a[5] = (short)bf16bits(xb.y);
        a[6] = (short)bf16bits(xb.z); a[7] = (short)bf16bits(xb.w);
        int kbase = kt * 32 + kgrp;
        #pragma unroll
        for (int t = 0; t < 5; ++t) {
            short8v b = *(const short8v*)&sBt[(t * 16 + jcol) * PAD + kbase];
            acc[t] = __builtin_amdgcn_mfma_f32_16x16x32_bf16(a, b, acc[t], 0, 0, 0);
        }
    }

    // h store: C layout col = l&15 (tile t -> col t*16+(l&15)), row = (l>>4)*4+reg.
    // Pack column pairs via shfl_xor(.,1); even sub-lanes write u32.
    int rbase = rowbase + (l >> 4) * 4;
    #pragma unroll
    for (int t = 0; t < 4; ++t) {
        #pragma unroll
        for (int r = 0; r < 4; ++r) {
            float v = acc[t][r];
            float w = __shfl_xor(v, 1);
            int row = rbase + r;
            if (!(l & 1) && row < N)
                hb_out[(size_t)row * 32 + t * 8 + (jcol >> 1)] = pack2bf(v, w);
        }
    }
    // alphas from tile 4: col 64 -> (l&15)==0, col 65 -> (l&15)==1
    #pragma unroll
    for (int r = 0; r < 4; ++r) {
        int row = rbase + r;
        if (row < N) {
            if (jcol == 0) alpha_src[row] = acc[4][r];
            if (jcol == 1) alpha_dst[row] = acc[4][r];
        }
    }
}

// ---------------------------------------------------------------------------
// Aggregation: wave per dst node. Chunk-of-64 lane-parallel softmax
// (lane = edge); gather phase: half-wave per edge, lane = u32 (2 bf16 feats).
// ---------------------------------------------------------------------------
__global__ __launch_bounds__(256) void aggregate(
    const int* __restrict__ row_ptr, const int* __restrict__ csr_src,
    const float* __restrict__ alpha_src, const float* __restrict__ alpha_dst,
    const unsigned* __restrict__ hb,    // [N][32] packed bf16x2
    const float* __restrict__ bias,     // [64]
    float* __restrict__ out,            // [N][64]
    int N) {
    int wid = threadIdx.x >> 6, lane = threadIdx.x & 63;
    int node = blockIdx.x * 4 + wid;
    if (node >= N) return;

    int beg = row_ptr[node], end = row_ptr[node + 1];
    float adst = alpha_dst[node];
    int half = lane >> 5, sub = lane & 31;

    float m = -1e30f, denom = 0.f;
    float aA0 = 0.f, aB0 = 0.f, aA1 = 0.f, aB1 = 0.f;
    float aA2 = 0.f, aB2 = 0.f, aA3 = 0.f, aB3 = 0.f;

    for (int c = beg; c < end; c += 64) {
        int cnt = end - c;
        cnt = (cnt < 64) ? cnt : 64;

        // --- lane-parallel logits (lane = edge) ---
        int s = 0;
        float el = -1e30f;
        if (lane < cnt) {
            s = csr_src[c + lane];
            float t = alpha_src[s] + adst;
            el = (t > 0.f) ? t : NEG_SLOPE * t;
        }
        float cm = el;
        #pragma unroll
        for (int off = 32; off; off >>= 1) cm = fmaxf(cm, __shfl_xor(cm, off));
        float mn = fmaxf(m, cm);
        float scale = __expf(m - mn);   // 0 on first chunk
        float p = (lane < cnt) ? __expf(el - mn) : 0.f;
        float ps = p;
        #pragma unroll
        for (int off = 32; off; off >>= 1) ps += __shfl_xor(ps, off);
        denom = denom * scale + ps;
        aA0 *= scale; aB0 *= scale; aA1 *= scale; aB1 *= scale;
        aA2 *= scale; aB2 *= scale; aA3 *= scale; aB3 *= scale;
        m = mn;

        // --- gather: 2 edges per step (half-wave each), 4 steps in flight ---
        int j = 0;
        for (; j + 8 <= cnt; j += 8) {
            int e0 = j + half, e1 = j + 2 + half, e2 = j + 4 + half, e3 = j + 6 + half;
            int s0 = __shfl(s, e0), s1 = __shfl(s, e1);
            int s2 = __shfl(s, e2), s3 = __shfl(s, e3);
            float p0 = __shfl(p, e0), p1 = __shfl(p, e1);
            float p2 = __shfl(p, e2), p3 = __shfl(p, e3);
            unsigned u0 = hb[(size_t)s0 * 32 + sub];
            unsigned u1 = hb[(size_t)s1 * 32 + sub];
            unsigned u2 = hb[(size_t)s2 * 32 + sub];
            unsigned u3 = hb[(size_t)s3 * 32 + sub];
            aA0 = fmaf(p0, blo(u0), aA0); aB0 = fmaf(p0, bhi(u0), aB0);
            aA1 = fmaf(p1, blo(u1), aA1); aB1 = fmaf(p1, bhi(u1), aB1);
            aA2 = fmaf(p2, blo(u2), aA2); aB2 = fmaf(p2, bhi(u2), aB2);
            aA3 = fmaf(p3, blo(u3), aA3); aB3 = fmaf(p3, bhi(u3), aB3);
        }
        for (; j < cnt; j += 2) {
            int e = j + half;
            int ec = (e < cnt) ? e : j;
            float pe = __shfl(p, ec);
            if (e >= cnt) pe = 0.f;
            int se = __shfl(s, ec);
            unsigned u = hb[(size_t)se * 32 + sub];
            aA0 = fmaf(pe, blo(u), aA0);
            aB0 = fmaf(pe, bhi(u), aB0);
        }
    }
    float accA = (aA0 + aA1) + (aA2 + aA3);
    float accB = (aB0 + aB1) + (aB2 + aB3);
    accA += __shfl_xor(accA, 32);
    accB += __shfl_xor(accB, 32);
    int srcl = lane >> 1;
    float vA = __shfl(accA, srcl);
    float vB = __shfl(accB, srcl);
    float val = (lane & 1) ? vB : vA;
    float r = (denom > 0.f) ? (val / denom) : 0.f;
    out[(size_t)node * 64 + lane] = tanhf(r + bias[lane]);
}

// ---------------------------------------------------------------------------
extern "C" void kernel_launch(void* const* d_in, const int* in_sizes, int n_in,
                              void* d_out, int out_size, void* d_ws, size_t ws_size,
                              hipStream_t stream) {
    const float* x      = (const float*)d_in[0];
    const int*   src    = (const int*)  d_in[1];
    const int*   dst    = (const int*)  d_in[2];
    const float* W1_src = (const float*)d_in[3];
    const float* W1_dst = (const float*)d_in[4];
    const float* a1_src = (const float*)d_in[5];
    const float* a1_dst = (const float*)d_in[6];
    const float* b1     = (const float*)d_in[7];
    const float* W2_src = (const float*)d_in[8];
    const float* W2_dst = (const float*)d_in[9];
    const float* a2_src = (const float*)d_in[10];
    const float* a2_dst = (const float*)d_in[11];
    const float* b2     = (const float*)d_in[12];
    float* out = (float*)d_out;

    const int N = in_sizes[0] / 128;
    const int E = in_sizes[1];
    const int NB = (N + 255) / 256;          // buckets (196)

    // workspace layout (256-byte aligned slices)
    char* ws = (char*)d_ws;
    size_t off = 0;
    auto alloc = [&](size_t bytes) {
        void* p = ws + off;
        off += (bytes + 255) & ~(size_t)255;
        return p;
    };
    unsigned* hbuf   = (unsigned*)alloc((size_t)N * 32 * 4);  // packed bf16 h
    float* bufB      = (float*)alloc((size_t)N * 64 * 4);     // h1; aliases ebuf
    float* alpha_src = (float*)alloc((size_t)N * 4);
    float* alpha_dst = (float*)alloc((size_t)N * 4);
    int*   row_ptr   = (int*)  alloc((size_t)(N + 1) * 4);
    int*   csr_src   = (int*)  alloc((size_t)E * 4);
    int*   bucket_cnt    = (int*)alloc(256 * 4);
    int*   bucket_base   = (int*)alloc(257 * 4);
    int*   bucket_cursor = (int*)alloc(256 * 4);
    unsigned* ebuf = (unsigned*)bufB;   // dead before bufB is first written
    (void)ws_size;

    const int eb3   = (E + EPB - 1) / EPB;   // bucket_scatter blocks
    const int aggb  = (N + 3) / 4;           // aggregate: 4 nodes/block
    const int mfb   = (N + 63) / 64;         // node_transform_mfma: 64 rows/block

    // ---- CSR build (counting sort; graph shared by both layers) ----
    init_counts<<<1, 256, 0, stream>>>(bucket_cnt);
    bucket_hist<<<256, 256, 0, stream>>>(dst, bucket_cnt, E);
    bucket_scan<<<1, 256, 0, stream>>>(bucket_cnt, bucket_base, bucket_cursor, NB);
    bucket_scatter<<<eb3, 256, 0, stream>>>(src, dst, bucket_cursor, ebuf, E);
    bucket_build<<<NB, 256, 0, stream>>>(ebuf, bucket_base, row_ptr, csr_src, N, E);

    // ---- Layer 1 ----
    node_transform_mfma<128><<<mfb, 256, 0, stream>>>(x, W1_src, a1_src, W1_dst, a1_dst,
                                                      hbuf, alpha_src, alpha_dst, N);
    aggregate<<<aggb, 256, 0, stream>>>(row_ptr, csr_src, alpha_src, alpha_dst,
                                        hbuf, b1, bufB, N);

    // ---- Layer 2 ----
    node_transform_mfma<64><<<mfb, 256, 0, stream>>>(bufB, W2_src, a2_src, W2_dst, a2_dst,
                                                     hbuf, alpha_src, alpha_dst, N);
    aggregate<<<aggb, 256, 0, stream>>>(row_ptr, csr_src, alpha_src, alpha_dst,
                                        hbuf, b2, out, N);
}

// Round 6
// 149.609 us; speedup vs baseline: 3.3209x; 1.0575x over previous
//
#include <hip/hip_runtime.h>
#include <hip/hip_bf16.h>

#define NEG_SLOPE 0.2f
#define EPB 4096   // edges per block in bucket_scatter (256 thr x 16)

typedef __attribute__((ext_vector_type(8))) short short8v;   // 8 bf16 bit-patterns
typedef __attribute__((ext_vector_type(4))) float f32x4;

__device__ inline float blo(unsigned u) { return __uint_as_float(u << 16); }
__device__ inline float bhi(unsigned u) { return __uint_as_float(u & 0xffff0000u); }
__device__ inline unsigned short bf16bits(float f) {
    __hip_bfloat16 b = __float2bfloat16(f);
    return *(unsigned short*)&b;
}
__device__ inline unsigned pack2bf(float e, float o) {
    return ((unsigned)bf16bits(o) << 16) | (unsigned)bf16bits(e);
}

// ---------------------------------------------------------------------------
// CSR build via bucketed counting sort. bucket(node) = node >> 8.
// ---------------------------------------------------------------------------
__global__ void init_counts(int* __restrict__ bucket_cnt) {
    bucket_cnt[threadIdx.x] = 0;
}

__global__ __launch_bounds__(256) void bucket_hist(const int* __restrict__ dst,
                                                   int* __restrict__ bucket_cnt, int E) {
    __shared__ int lh[256];
    int tid = threadIdx.x;
    lh[tid] = 0;
    __syncthreads();
    for (int e = blockIdx.x * 256 + tid; e < E; e += gridDim.x * 256)
        atomicAdd(&lh[dst[e] >> 8], 1);
    __syncthreads();
    if (lh[tid]) atomicAdd(&bucket_cnt[tid], lh[tid]);
}

__global__ __launch_bounds__(256) void bucket_scan(const int* __restrict__ bucket_cnt,
                                                   int* __restrict__ bucket_base,
                                                   int* __restrict__ bucket_cursor, int NB) {
    __shared__ int tmp[256];
    int tid = threadIdx.x;
    int v = (tid < NB) ? bucket_cnt[tid] : 0;
    tmp[tid] = v;
    __syncthreads();
    for (int off = 1; off < 256; off <<= 1) {
        int t = (tid >= off) ? tmp[tid - off] : 0;
        __syncthreads();
        tmp[tid] += t;
        __syncthreads();
    }
    int excl = tmp[tid] - v;
    bucket_base[tid] = excl;
    bucket_cursor[tid] = excl;
    if (tid == 255) bucket_base[256] = tmp[255];   // == E
}

// ebuf entry = (dst&255)<<16 | src   (requires N <= 65536)
__global__ __launch_bounds__(256) void bucket_scatter(const int* __restrict__ src,
                                                      const int* __restrict__ dst,
                                                      int* __restrict__ bucket_cursor,
                                                      unsigned* __restrict__ ebuf, int E) {
    __shared__ int lhist[256];
    __shared__ int lbase[256];
    int tid = threadIdx.x;
    lhist[tid] = 0;
    __syncthreads();
    int base = blockIdx.x * EPB;
    int bkt[16], rank[16];
    unsigned pack[16];
    #pragma unroll
    for (int i = 0; i < 16; ++i) {
        int e = base + i * 256 + tid;
        bkt[i] = -1;
        if (e < E) {
            int d = dst[e], s = src[e];
            bkt[i]  = d >> 8;
            pack[i] = ((unsigned)(d & 255) << 16) | (unsigned)s;
            rank[i] = atomicAdd(&lhist[bkt[i]], 1);
        }
    }
    __syncthreads();
    int cnt = lhist[tid];
    if (cnt) lbase[tid] = atomicAdd(&bucket_cursor[tid], cnt);
    __syncthreads();
    #pragma unroll
    for (int i = 0; i < 16; ++i)
        if (bkt[i] >= 0) ebuf[lbase[bkt[i]] + rank[i]] = pack[i];
}

__global__ __launch_bounds__(256) void bucket_build(const unsigned* __restrict__ ebuf,
                                                    const int* __restrict__ bucket_base,
                                                    int* __restrict__ row_ptr,
                                                    int* __restrict__ csr_src,
                                                    int N, int E) {
    __shared__ int deg[256];
    __shared__ int cur[256];
    __shared__ int tmp[256];
    int b = blockIdx.x, tid = threadIdx.x;
    int ebase = bucket_base[b], eend = bucket_base[b + 1];
    deg[tid] = 0;
    __syncthreads();
    for (int e = ebase + tid; e < eend; e += 256)
        atomicAdd(&deg[ebuf[e] >> 16], 1);
    __syncthreads();
    int v = deg[tid];
    tmp[tid] = v;
    __syncthreads();
    for (int off = 1; off < 256; off <<= 1) {
        int t = (tid >= off) ? tmp[tid - off] : 0;
        __syncthreads();
        tmp[tid] += t;
        __syncthreads();
    }
    int excl = tmp[tid] - v;
    int node = b * 256 + tid;
    if (node < N) row_ptr[node] = ebase + excl;
    if (b == 0 && tid == 0) row_ptr[N] = E;
    cur[tid] = excl;
    __syncthreads();
    for (int e = ebase + tid; e < eend; e += 256) {
        unsigned pk = ebuf[e];
        int r = atomicAdd(&cur[pk >> 16], 1);
        csr_src[ebase + r] = (int)(pk & 0xFFFFu);
    }
}

// ---------------------------------------------------------------------------
// Node transform via MFMA (bf16 in, fp32 accum):
//   h = x@W_src (packed bf16 out), alpha_src = x@(W_src@a_src) [col 64],
//   alpha_dst = x@(W_dst@a_dst) [col 65].
// INBF16: x is [N][K] packed bf16 (u16); else fp32.
// 4 waves/block, wave = 16 rows x 80 cols (5 MFMA col-tiles).
// ---------------------------------------------------------------------------
template <int K, bool INBF16>
__global__ __launch_bounds__(256) void node_transform_mfma(
    const void* __restrict__ x_,        // [N][K] fp32 or bf16
    const float* __restrict__ W_src,    // [K][64]
    const float* __restrict__ a_src,    // [64]
    const float* __restrict__ W_dst,    // [K][64]
    const float* __restrict__ a_dst,    // [64]
    unsigned* __restrict__ hb_out,      // [N][32] packed bf16x2
    float* __restrict__ alpha_src,      // [N]
    float* __restrict__ alpha_dst,      // [N]
    int N) {
    constexpr int PAD = K + 8;
    __shared__ unsigned short sBt[80 * PAD];

    int tid = threadIdx.x;
    // cols 0..63 = W_src^T (coalesced global read, ushort LDS write)
    for (int i = tid; i < 64 * K; i += 256) {
        int k = i >> 6, j = i & 63;
        sBt[j * PAD + k] = bf16bits(W_src[i]);
    }
    // col 64 = W_src@a_src, col 65 = W_dst@a_dst
    for (int i = tid; i < 2 * K; i += 256) {
        int which = (i >= K) ? 1 : 0;
        int k = i - which * K;
        const float* Wr = (which ? W_dst : W_src) + k * 64;
        const float* av = which ? a_dst : a_src;
        float s = 0.f;
        #pragma unroll
        for (int j = 0; j < 64; ++j) s += Wr[j] * av[j];
        sBt[(64 + which) * PAD + k] = bf16bits(s);
    }
    // cols 66..79 = 0
    for (int i = tid; i < 14 * K; i += 256) {
        int j = 66 + i / K, k = i % K;
        sBt[j * PAD + k] = 0;
    }
    __syncthreads();

    int wid = tid >> 6, l = tid & 63;
    int rowbase = blockIdx.x * 64 + wid * 16;
    int r_load = rowbase + (l & 15);
    if (r_load >= N) r_load = N - 1;          // clamp (stores are guarded)
    int kgrp = (l >> 4) * 8;

    f32x4 acc[5];
    #pragma unroll
    for (int t = 0; t < 5; ++t) acc[t] = (f32x4){0.f, 0.f, 0.f, 0.f};

    const float* xr32 = (const float*)x_ + (size_t)r_load * K + kgrp;
    const unsigned short* xr16 = (const unsigned short*)x_ + (size_t)r_load * K + kgrp;
    int jcol = l & 15;
    #pragma unroll
    for (int kt = 0; kt < K / 32; ++kt) {
        short8v a;
        if constexpr (INBF16) {
            a = *(const short8v*)(xr16 + kt * 32);
        } else {
            float4 xa = *(const float4*)(xr32 + kt * 32);
            float4 xb = *(const float4*)(xr32 + kt * 32 + 4);
            a[0] = (short)bf16bits(xa.x); a[1] = (short)bf16bits(xa.y);
            a[2] = (short)bf16bits(xa.z); a[3] = (short)bf16bits(xa.w);
            a[4] = (short)bf16bits(xb.x); a[5] = (short)bf16bits(xb.y);
            a[6] = (short)bf16bits(xb.z); a[7] = (short)bf16bits(xb.w);
        }
        int kbase = kt * 32 + kgrp;
        #pragma unroll
        for (int t = 0; t < 5; ++t) {
            short8v b = *(const short8v*)&sBt[(t * 16 + jcol) * PAD + kbase];
            acc[t] = __builtin_amdgcn_mfma_f32_16x16x32_bf16(a, b, acc[t], 0, 0, 0);
        }
    }

    // h store: C layout col = l&15 (tile t -> col t*16+(l&15)), row = (l>>4)*4+reg.
    int rbase = rowbase + (l >> 4) * 4;
    #pragma unroll
    for (int t = 0; t < 4; ++t) {
        #pragma unroll
        for (int r = 0; r < 4; ++r) {
            float v = acc[t][r];
            float w = __shfl_xor(v, 1);
            int row = rbase + r;
            if (!(l & 1) && row < N)
                hb_out[(size_t)row * 32 + t * 8 + (jcol >> 1)] = pack2bf(v, w);
        }
    }
    // alphas from tile 4: col 64 -> (l&15)==0, col 65 -> (l&15)==1
    #pragma unroll
    for (int r = 0; r < 4; ++r) {
        int row = rbase + r;
        if (row < N) {
            if (jcol == 0) alpha_src[row] = acc[4][r];
            if (jcol == 1) alpha_dst[row] = acc[4][r];
        }
    }
}

// ---------------------------------------------------------------------------
// Aggregation: wave per dst node. Direct-exp softmax (no max tracking:
// logits are O(10), fp32-exp safe; ratio identical to max-subtracted form).
// Logit phase lane = edge; gather phase half-wave per edge, lane = u32.
// Lanes >= cnt carry p=0,s=0 so 8-edge broadcast groups need no guards.
// OUTBF16: write packed bf16 [N][32] (next layer's GEMM input); else fp32 [N][64].
// ---------------------------------------------------------------------------
template <bool OUTBF16>
__global__ __launch_bounds__(256) void aggregate(
    const int* __restrict__ row_ptr, const int* __restrict__ csr_src,
    const float* __restrict__ alpha_src, const float* __restrict__ alpha_dst,
    const unsigned* __restrict__ hb,    // [N][32] packed bf16x2
    const float* __restrict__ bias,     // [64]
    void* __restrict__ out_,            // fp32 [N][64] or packed bf16 [N][32]
    int N) {
    int wid = threadIdx.x >> 6, lane = threadIdx.x & 63;
    int node = blockIdx.x * 4 + wid;
    if (node >= N) return;

    int beg = row_ptr[node], end = row_ptr[node + 1];
    float adst = alpha_dst[node];
    int half = lane >> 5, sub = lane & 31;

    float dL = 0.f;   // per-lane denominator partial
    float aA0 = 0.f, aB0 = 0.f, aA1 = 0.f, aB1 = 0.f;
    float aA2 = 0.f, aB2 = 0.f, aA3 = 0.f, aB3 = 0.f;

    for (int c = beg; c < end; c += 64) {
        int cnt = end - c;
        cnt = (cnt < 64) ? cnt : 64;

        // --- lane-parallel numerators (lane = edge) ---
        int s = 0;
        float p = 0.f;
        if (lane < cnt) {
            s = csr_src[c + lane];
            float t = alpha_src[s] + adst;
            t = (t > 0.f) ? t : NEG_SLOPE * t;
            p = __expf(fminf(t, 60.f));
            dL += p;
        }

        // --- gather: 8 edges per group, 4 loads in flight, no tail guards ---
        for (int j = 0; j < cnt; j += 8) {
            int e0 = j + half, e1 = j + 2 + half, e2 = j + 4 + half, e3 = j + 6 + half;
            int s0 = __shfl(s, e0), s1 = __shfl(s, e1);
            int s2 = __shfl(s, e2), s3 = __shfl(s, e3);
            float p0 = __shfl(p, e0), p1 = __shfl(p, e1);
            float p2 = __shfl(p, e2), p3 = __shfl(p, e3);
            unsigned u0 = hb[(size_t)s0 * 32 + sub];
            unsigned u1 = hb[(size_t)s1 * 32 + sub];
            unsigned u2 = hb[(size_t)s2 * 32 + sub];
            unsigned u3 = hb[(size_t)s3 * 32 + sub];
            aA0 = fmaf(p0, blo(u0), aA0); aB0 = fmaf(p0, bhi(u0), aB0);
            aA1 = fmaf(p1, blo(u1), aA1); aB1 = fmaf(p1, bhi(u1), aB1);
            aA2 = fmaf(p2, blo(u2), aA2); aB2 = fmaf(p2, bhi(u2), aB2);
            aA3 = fmaf(p3, blo(u3), aA3); aB3 = fmaf(p3, bhi(u3), aB3);
        }
    }
    // denominator: one reduce at the end
    float denom = dL;
    #pragma unroll
    for (int off = 32; off; off >>= 1) denom += __shfl_xor(denom, off);

    float accA = (aA0 + aA1) + (aA2 + aA3);
    float accB = (aB0 + aB1) + (aB2 + aB3);
    accA += __shfl_xor(accA, 32);
    accB += __shfl_xor(accB, 32);
    int srcl = lane >> 1;
    float vA = __shfl(accA, srcl);
    float vB = __shfl(accB, srcl);
    float val = (lane & 1) ? vB : vA;
    float r = (denom > 0.f) ? (val / denom) : 0.f;
    float fv = tanhf(r + bias[lane]);

    if constexpr (OUTBF16) {
        float fw = __shfl_xor(fv, 1);
        if (!(lane & 1))
            ((unsigned*)out_)[(size_t)node * 32 + (lane >> 1)] = pack2bf(fv, fw);
    } else {
        ((float*)out_)[(size_t)node * 64 + lane] = fv;
    }
}

// ---------------------------------------------------------------------------
extern "C" void kernel_launch(void* const* d_in, const int* in_sizes, int n_in,
                              void* d_out, int out_size, void* d_ws, size_t ws_size,
                              hipStream_t stream) {
    const float* x      = (const float*)d_in[0];
    const int*   src    = (const int*)  d_in[1];
    const int*   dst    = (const int*)  d_in[2];
    const float* W1_src = (const float*)d_in[3];
    const float* W1_dst = (const float*)d_in[4];
    const float* a1_src = (const float*)d_in[5];
    const float* a1_dst = (const float*)d_in[6];
    const float* b1     = (const float*)d_in[7];
    const float* W2_src = (const float*)d_in[8];
    const float* W2_dst = (const float*)d_in[9];
    const float* a2_src = (const float*)d_in[10];
    const float* a2_dst = (const float*)d_in[11];
    const float* b2     = (const float*)d_in[12];
    float* out = (float*)d_out;

    const int N = in_sizes[0] / 128;
    const int E = in_sizes[1];
    const int NB = (N + 255) / 256;          // buckets (196)

    // workspace layout (256-byte aligned slices)
    char* ws = (char*)d_ws;
    size_t off = 0;
    auto alloc = [&](size_t bytes) {
        void* p = ws + off;
        off += (bytes + 255) & ~(size_t)255;
        return p;
    };
    unsigned* hbuf   = (unsigned*)alloc((size_t)N * 32 * 4);  // packed bf16 h
    unsigned* h1buf  = (unsigned*)alloc((size_t)N * 32 * 4);  // packed bf16 h1; aliases ebuf
    float* alpha_src = (float*)alloc((size_t)N * 4);
    float* alpha_dst = (float*)alloc((size_t)N * 4);
    int*   row_ptr   = (int*)  alloc((size_t)(N + 1) * 4);
    int*   csr_src   = (int*)  alloc((size_t)E * 4);
    int*   bucket_cnt    = (int*)alloc(256 * 4);
    int*   bucket_base   = (int*)alloc(257 * 4);
    int*   bucket_cursor = (int*)alloc(256 * 4);
    unsigned* ebuf = (unsigned*)alloc((size_t)E * 4);  // edge staging (CSR build only)
    (void)ws_size;

    const int eb3   = (E + EPB - 1) / EPB;   // bucket_scatter blocks
    const int aggb  = (N + 3) / 4;           // aggregate: 4 nodes/block
    const int mfb   = (N + 63) / 64;         // node_transform_mfma: 64 rows/block

    // ---- CSR build (counting sort; graph shared by both layers) ----
    init_counts<<<1, 256, 0, stream>>>(bucket_cnt);
    bucket_hist<<<256, 256, 0, stream>>>(dst, bucket_cnt, E);
    bucket_scan<<<1, 256, 0, stream>>>(bucket_cnt, bucket_base, bucket_cursor, NB);
    bucket_scatter<<<eb3, 256, 0, stream>>>(src, dst, bucket_cursor, ebuf, E);
    bucket_build<<<NB, 256, 0, stream>>>(ebuf, bucket_base, row_ptr, csr_src, N, E);

    // ---- Layer 1 ----
    node_transform_mfma<128, false><<<mfb, 256, 0, stream>>>(
        x, W1_src, a1_src, W1_dst, a1_dst, hbuf, alpha_src, alpha_dst, N);
    aggregate<true><<<aggb, 256, 0, stream>>>(row_ptr, csr_src, alpha_src, alpha_dst,
                                              hbuf, b1, h1buf, N);

    // ---- Layer 2 ----
    node_transform_mfma<64, true><<<mfb, 256, 0, stream>>>(
        h1buf, W2_src, a2_src, W2_dst, a2_dst, hbuf, alpha_src, alpha_dst, N);
    aggregate<false><<<aggb, 256, 0, stream>>>(row_ptr, csr_src, alpha_src, alpha_dst,
                                               hbuf, b2, out, N);
}

// Round 7
// 148.487 us; speedup vs baseline: 3.3460x; 1.0076x over previous
//
#include <hip/hip_runtime.h>
#include <hip/hip_bf16.h>

#define NEG_SLOPE 0.2f
#define EPB 4096   // edges per block in bucket_scatter (256 thr x 16)

typedef __attribute__((ext_vector_type(8))) short short8v;   // 8 bf16 bit-patterns
typedef __attribute__((ext_vector_type(4))) float f32x4;

__device__ inline float blo(unsigned u) { return __uint_as_float(u << 16); }
__device__ inline float bhi(unsigned u) { return __uint_as_float(u & 0xffff0000u); }
__device__ inline unsigned short bf16bits(float f) {
    __hip_bfloat16 b = __float2bfloat16(f);
    return *(unsigned short*)&b;
}
__device__ inline unsigned pack2bf(float e, float o) {
    return ((unsigned)bf16bits(o) << 16) | (unsigned)bf16bits(e);
}

// ---------------------------------------------------------------------------
// CSR build via bucketed counting sort. bucket(node) = node >> 8.
// ---------------------------------------------------------------------------
__global__ void init_counts(int* __restrict__ bucket_cnt) {
    bucket_cnt[threadIdx.x] = 0;
}

__global__ __launch_bounds__(256) void bucket_hist(const int* __restrict__ dst,
                                                   int* __restrict__ bucket_cnt, int E) {
    __shared__ int lh[256];
    int tid = threadIdx.x;
    lh[tid] = 0;
    __syncthreads();
    for (int e = blockIdx.x * 256 + tid; e < E; e += gridDim.x * 256)
        atomicAdd(&lh[dst[e] >> 8], 1);
    __syncthreads();
    if (lh[tid]) atomicAdd(&bucket_cnt[tid], lh[tid]);
}

__global__ __launch_bounds__(256) void bucket_scan(const int* __restrict__ bucket_cnt,
                                                   int* __restrict__ bucket_base,
                                                   int* __restrict__ bucket_cursor, int NB) {
    __shared__ int tmp[256];
    int tid = threadIdx.x;
    int v = (tid < NB) ? bucket_cnt[tid] : 0;
    tmp[tid] = v;
    __syncthreads();
    for (int off = 1; off < 256; off <<= 1) {
        int t = (tid >= off) ? tmp[tid - off] : 0;
        __syncthreads();
        tmp[tid] += t;
        __syncthreads();
    }
    int excl = tmp[tid] - v;
    bucket_base[tid] = excl;
    bucket_cursor[tid] = excl;
    if (tid == 255) bucket_base[256] = tmp[255];   // == E
}

// ebuf entry = (dst&255)<<16 | src   (requires N <= 65536)
__global__ __launch_bounds__(256) void bucket_scatter(const int* __restrict__ src,
                                                      const int* __restrict__ dst,
                                                      int* __restrict__ bucket_cursor,
                                                      unsigned* __restrict__ ebuf, int E) {
    __shared__ int lhist[256];
    __shared__ int lbase[256];
    int tid = threadIdx.x;
    lhist[tid] = 0;
    __syncthreads();
    int base = blockIdx.x * EPB;
    int bkt[16], rank[16];
    unsigned pack[16];
    #pragma unroll
    for (int i = 0; i < 16; ++i) {
        int e = base + i * 256 + tid;
        bkt[i] = -1;
        if (e < E) {
            int d = dst[e], s = src[e];
            bkt[i]  = d >> 8;
            pack[i] = ((unsigned)(d & 255) << 16) | (unsigned)s;
            rank[i] = atomicAdd(&lhist[bkt[i]], 1);
        }
    }
    __syncthreads();
    int cnt = lhist[tid];
    if (cnt) lbase[tid] = atomicAdd(&bucket_cursor[tid], cnt);
    __syncthreads();
    #pragma unroll
    for (int i = 0; i < 16; ++i)
        if (bkt[i] >= 0) ebuf[lbase[bkt[i]] + rank[i]] = pack[i];
}

__global__ __launch_bounds__(256) void bucket_build(const unsigned* __restrict__ ebuf,
                                                    const int* __restrict__ bucket_base,
                                                    int* __restrict__ row_ptr,
                                                    int* __restrict__ csr_src,
                                                    int N, int E) {
    __shared__ int deg[256];
    __shared__ int cur[256];
    __shared__ int tmp[256];
    int b = blockIdx.x, tid = threadIdx.x;
    int ebase = bucket_base[b], eend = bucket_base[b + 1];
    deg[tid] = 0;
    __syncthreads();
    for (int e = ebase + tid; e < eend; e += 256)
        atomicAdd(&deg[ebuf[e] >> 16], 1);
    __syncthreads();
    int v = deg[tid];
    tmp[tid] = v;
    __syncthreads();
    for (int off = 1; off < 256; off <<= 1) {
        int t = (tid >= off) ? tmp[tid - off] : 0;
        __syncthreads();
        tmp[tid] += t;
        __syncthreads();
    }
    int excl = tmp[tid] - v;
    int node = b * 256 + tid;
    if (node < N) row_ptr[node] = ebase + excl;
    if (b == 0 && tid == 0) row_ptr[N] = E;
    cur[tid] = excl;
    __syncthreads();
    for (int e = ebase + tid; e < eend; e += 256) {
        unsigned pk = ebuf[e];
        int r = atomicAdd(&cur[pk >> 16], 1);
        csr_src[ebase + r] = (int)(pk & 0xFFFFu);
    }
}

// ---------------------------------------------------------------------------
// Node transform via MFMA (bf16 in, fp32 accum):
//   h = x@W_src (packed bf16 out), alpha_src = x@(W_src@a_src) [col 64],
//   alpha_dst = x@(W_dst@a_dst) [col 65].
// x tile staged into LDS with coalesced row-major loads; fragments read via
// ds_read_b128 (row stride = (K+8)*2B = odd multiple of 16B -> conflict-free).
// 4 waves/block, wave = 16 rows x 80 cols (5 MFMA col-tiles).
// ---------------------------------------------------------------------------
template <int K, bool INBF16>
__global__ __launch_bounds__(256) void node_transform_mfma(
    const void* __restrict__ x_,        // [N][K] fp32 or packed bf16
    const float* __restrict__ W_src,    // [K][64]
    const float* __restrict__ a_src,    // [64]
    const float* __restrict__ W_dst,    // [K][64]
    const float* __restrict__ a_dst,    // [64]
    unsigned* __restrict__ hb_out,      // [N][32] packed bf16x2
    float* __restrict__ alpha_src,      // [N]
    float* __restrict__ alpha_dst,      // [N]
    int N) {
    constexpr int PAD = K + 8;
    __shared__ unsigned short sBt[80 * PAD];
    __shared__ unsigned short sX[64 * PAD];

    int tid = threadIdx.x;
    // cols 0..63 = W_src^T (coalesced global read)
    for (int i = tid; i < 64 * K; i += 256) {
        int k = i >> 6, j = i & 63;
        sBt[j * PAD + k] = bf16bits(W_src[i]);
    }
    // col 64 = W_src@a_src, col 65 = W_dst@a_dst
    for (int i = tid; i < 2 * K; i += 256) {
        int which = (i >= K) ? 1 : 0;
        int k = i - which * K;
        const float* Wr = (which ? W_dst : W_src) + k * 64;
        const float* av = which ? a_dst : a_src;
        float s = 0.f;
        #pragma unroll
        for (int j = 0; j < 64; ++j) s += Wr[j] * av[j];
        sBt[(64 + which) * PAD + k] = bf16bits(s);
    }
    // cols 66..79 = 0
    for (int i = tid; i < 14 * K; i += 256) {
        int j = 66 + i / K, k = i % K;
        sBt[j * PAD + k] = 0;
    }
    // stage x tile (64 rows), fully coalesced global reads
    if constexpr (!INBF16) {
        const float* xb = (const float*)x_;
        for (int idx = tid; idx < 64 * K / 4; idx += 256) {
            int row = (idx * 4) / K, col = (idx * 4) % K;
            int g = blockIdx.x * 64 + row;
            const float4 f = *(const float4*)(xb + (size_t)((g < N) ? g : N - 1) * K + col);
            unsigned short* d = &sX[row * PAD + col];
            d[0] = bf16bits(f.x); d[1] = bf16bits(f.y);
            d[2] = bf16bits(f.z); d[3] = bf16bits(f.w);
        }
    } else {
        const unsigned short* xb = (const unsigned short*)x_;
        for (int idx = tid; idx < 64 * K / 8; idx += 256) {
            int row = (idx * 8) / K, col = (idx * 8) % K;
            int g = blockIdx.x * 64 + row;
            short8v v = *(const short8v*)(xb + (size_t)((g < N) ? g : N - 1) * K + col);
            *(short8v*)&sX[row * PAD + col] = v;
        }
    }
    __syncthreads();

    int wid = tid >> 6, l = tid & 63;
    int rowbase = blockIdx.x * 64 + wid * 16;
    int jcol = l & 15;

    f32x4 acc[5];
    #pragma unroll
    for (int t = 0; t < 5; ++t) acc[t] = (f32x4){0.f, 0.f, 0.f, 0.f};

    const unsigned short* xrow = &sX[(wid * 16 + (l & 15)) * PAD + (l >> 4) * 8];
    #pragma unroll
    for (int kt = 0; kt < K / 32; ++kt) {
        short8v a = *(const short8v*)(xrow + kt * 32);
        int kbase = kt * 32 + (l >> 4) * 8;
        #pragma unroll
        for (int t = 0; t < 5; ++t) {
            short8v b = *(const short8v*)&sBt[(t * 16 + jcol) * PAD + kbase];
            acc[t] = __builtin_amdgcn_mfma_f32_16x16x32_bf16(a, b, acc[t], 0, 0, 0);
        }
    }

    // h store: C layout col = l&15 (tile t -> col t*16+(l&15)), row = (l>>4)*4+reg.
    int rbase = rowbase + (l >> 4) * 4;
    #pragma unroll
    for (int t = 0; t < 4; ++t) {
        #pragma unroll
        for (int r = 0; r < 4; ++r) {
            float v = acc[t][r];
            float w = __shfl_xor(v, 1);
            int row = rbase + r;
            if (!(l & 1) && row < N)
                hb_out[(size_t)row * 32 + t * 8 + (jcol >> 1)] = pack2bf(v, w);
        }
    }
    // alphas from tile 4: col 64 -> (l&15)==0, col 65 -> (l&15)==1
    #pragma unroll
    for (int r = 0; r < 4; ++r) {
        int row = rbase + r;
        if (row < N) {
            if (jcol == 0) alpha_src[row] = acc[4][r];
            if (jcol == 1) alpha_dst[row] = acc[4][r];
        }
    }
}

// ---------------------------------------------------------------------------
// Aggregation: wave per dst node. Direct-exp softmax (logits O(10), fp32-exp
// safe; ratio identical to max-subtracted form). Logit phase lane = edge;
// gather phase half-wave per edge, lane = u32 (2 bf16 feats); 16-edge groups
// keep 8 independent gathers in flight. Lanes >= cnt carry p=0,s=0 -> no
// tail guards. OUTBF16: write packed bf16 [N][32]; else fp32 [N][64].
// ---------------------------------------------------------------------------
template <bool OUTBF16>
__global__ __launch_bounds__(256) void aggregate(
    const int* __restrict__ row_ptr, const int* __restrict__ csr_src,
    const float* __restrict__ alpha_src, const float* __restrict__ alpha_dst,
    const unsigned* __restrict__ hb,    // [N][32] packed bf16x2
    const float* __restrict__ bias,     // [64]
    void* __restrict__ out_,            // fp32 [N][64] or packed bf16 [N][32]
    int N) {
    int wid = threadIdx.x >> 6, lane = threadIdx.x & 63;
    int node = blockIdx.x * 4 + wid;
    if (node >= N) return;

    int beg = row_ptr[node], end = row_ptr[node + 1];
    float adst = alpha_dst[node];
    int half = lane >> 5, sub = lane & 31;

    float dL = 0.f;   // per-lane denominator partial
    float aA[4] = {0.f, 0.f, 0.f, 0.f};
    float aB[4] = {0.f, 0.f, 0.f, 0.f};

    for (int c = beg; c < end; c += 64) {
        int cnt = end - c;
        cnt = (cnt < 64) ? cnt : 64;

        // --- lane-parallel numerators (lane = edge) ---
        int s = 0;
        float p = 0.f;
        if (lane < cnt) {
            s = csr_src[c + lane];
            float t = alpha_src[s] + adst;
            t = (t > 0.f) ? t : NEG_SLOPE * t;
            p = __expf(fminf(t, 60.f));
            dL += p;
        }

        // --- gather: 16 edges per group, 8 loads in flight, no tail guards ---
        for (int j = 0; j < cnt; j += 16) {
            int   sv[8];
            float pv[8];
            unsigned uv[8];
            #pragma unroll
            for (int i = 0; i < 8; ++i) {
                int e = j + 2 * i + half;
                sv[i] = __shfl(s, e);
                pv[i] = __shfl(p, e);
            }
            #pragma unroll
            for (int i = 0; i < 8; ++i)
                uv[i] = hb[(size_t)sv[i] * 32 + sub];
            #pragma unroll
            for (int i = 0; i < 8; ++i) {
                aA[i & 3] = fmaf(pv[i], blo(uv[i]), aA[i & 3]);
                aB[i & 3] = fmaf(pv[i], bhi(uv[i]), aB[i & 3]);
            }
        }
    }
    // denominator: one reduce at the end
    float denom = dL;
    #pragma unroll
    for (int off = 32; off; off >>= 1) denom += __shfl_xor(denom, off);

    float accA = (aA[0] + aA[1]) + (aA[2] + aA[3]);
    float accB = (aB[0] + aB[1]) + (aB[2] + aB[3]);
    accA += __shfl_xor(accA, 32);
    accB += __shfl_xor(accB, 32);
    int srcl = lane >> 1;
    float vA = __shfl(accA, srcl);
    float vB = __shfl(accB, srcl);
    float val = (lane & 1) ? vB : vA;
    float r = (denom > 0.f) ? (val / denom) : 0.f;
    float fv = tanhf(r + bias[lane]);

    if constexpr (OUTBF16) {
        float fw = __shfl_xor(fv, 1);
        if (!(lane & 1))
            ((unsigned*)out_)[(size_t)node * 32 + (lane >> 1)] = pack2bf(fv, fw);
    } else {
        ((float*)out_)[(size_t)node * 64 + lane] = fv;
    }
}

// ---------------------------------------------------------------------------
extern "C" void kernel_launch(void* const* d_in, const int* in_sizes, int n_in,
                              void* d_out, int out_size, void* d_ws, size_t ws_size,
                              hipStream_t stream) {
    const float* x      = (const float*)d_in[0];
    const int*   src    = (const int*)  d_in[1];
    const int*   dst    = (const int*)  d_in[2];
    const float* W1_src = (const float*)d_in[3];
    const float* W1_dst = (const float*)d_in[4];
    const float* a1_src = (const float*)d_in[5];
    const float* a1_dst = (const float*)d_in[6];
    const float* b1     = (const float*)d_in[7];
    const float* W2_src = (const float*)d_in[8];
    const float* W2_dst = (const float*)d_in[9];
    const float* a2_src = (const float*)d_in[10];
    const float* a2_dst = (const float*)d_in[11];
    const float* b2     = (const float*)d_in[12];
    float* out = (float*)d_out;

    const int N = in_sizes[0] / 128;
    const int E = in_sizes[1];
    const int NB = (N + 255) / 256;          // buckets (196)

    // workspace layout (256-byte aligned slices)
    char* ws = (char*)d_ws;
    size_t off = 0;
    auto alloc = [&](size_t bytes) {
        void* p = ws + off;
        off += (bytes + 255) & ~(size_t)255;
        return p;
    };
    unsigned* hbuf   = (unsigned*)alloc((size_t)N * 32 * 4);  // packed bf16 h
    unsigned* h1buf  = (unsigned*)alloc((size_t)N * 32 * 4);  // packed bf16 h1
    float* alpha_src = (float*)alloc((size_t)N * 4);
    float* alpha_dst = (float*)alloc((size_t)N * 4);
    int*   row_ptr   = (int*)  alloc((size_t)(N + 1) * 4);
    int*   csr_src   = (int*)  alloc((size_t)E * 4);
    int*   bucket_cnt    = (int*)alloc(256 * 4);
    int*   bucket_base   = (int*)alloc(257 * 4);
    int*   bucket_cursor = (int*)alloc(256 * 4);
    unsigned* ebuf = (unsigned*)alloc((size_t)E * 4);  // edge staging (CSR build only)
    (void)ws_size;

    const int eb3   = (E + EPB - 1) / EPB;   // bucket_scatter blocks
    const int aggb  = (N + 3) / 4;           // aggregate: 4 nodes/block
    const int mfb   = (N + 63) / 64;         // node_transform_mfma: 64 rows/block

    // ---- CSR build (counting sort; graph shared by both layers) ----
    init_counts<<<1, 256, 0, stream>>>(bucket_cnt);
    bucket_hist<<<256, 256, 0, stream>>>(dst, bucket_cnt, E);
    bucket_scan<<<1, 256, 0, stream>>>(bucket_cnt, bucket_base, bucket_cursor, NB);
    bucket_scatter<<<eb3, 256, 0, stream>>>(src, dst, bucket_cursor, ebuf, E);
    bucket_build<<<NB, 256, 0, stream>>>(ebuf, bucket_base, row_ptr, csr_src, N, E);

    // ---- Layer 1 ----
    node_transform_mfma<128, false><<<mfb, 256, 0, stream>>>(
        x, W1_src, a1_src, W1_dst, a1_dst, hbuf, alpha_src, alpha_dst, N);
    aggregate<true><<<aggb, 256, 0, stream>>>(row_ptr, csr_src, alpha_src, alpha_dst,
                                              hbuf, b1, h1buf, N);

    // ---- Layer 2 ----
    node_transform_mfma<64, true><<<mfb, 256, 0, stream>>>(
        h1buf, W2_src, a2_src, W2_dst, a2_dst, hbuf, alpha_src, alpha_dst, N);
    aggregate<false><<<aggb, 256, 0, stream>>>(row_ptr, csr_src, alpha_src, alpha_dst,
                                               hbuf, b2, out, N);
}